// Round 15
// baseline (693.991 us; speedup 1.0000x reference)
//
#include <hip/hip_runtime.h>
#include <hip/hip_fp16.h>

#define NNODES 100000
#define NEDGES 1600000
#define NGRAPH 128
#define CIN 128
#define CH 64
#define COUT 7
#define NSTACK 9

#define NB 391      // buckets of 256 nodes: ceil(100000/256)
#define CHUNK 2048  // edges per histogram/scatter block
#define NC 782      // ceil(1600000/2048)

// ---------------- merged: P1 bucket histogram (LDS only) + layer-0 GEMM ----------------
// GEMM half: h-row addresses are wave-uniform (readfirstlane) -> compiler emits
// scalar s_load for h values, feeding v_fmac's SGPR operand directly. No
// per-lane h loads, no readlane broadcast: ~1 VALU op per FMA.
template <int K>
__global__ __launch_bounds__(256) void hist_gemm_kernel(const int* __restrict__ dst,
                                                        int* __restrict__ hist, int E,
                                                        const float* __restrict__ h,
                                                        const float* __restrict__ W,
                                                        __half* __restrict__ m, int N,
                                                        int histBlocks) {
    __shared__ float Ws[K * 64];
    __shared__ int lh[NB];
    if (blockIdx.x < (unsigned)histBlocks) {
        for (int i = threadIdx.x; i < NB; i += 256) lh[i] = 0;
        __syncthreads();
        int e0 = blockIdx.x * CHUNK;
        int e1 = min(e0 + CHUNK, E);
        for (int e = e0 + threadIdx.x; e < e1; e += 256)
            atomicAdd(&lh[dst[e] >> 8], 1);   // LDS atomic
        __syncthreads();
        for (int i = threadIdx.x; i < NB; i += 256) hist[i * NC + (int)blockIdx.x] = lh[i];
        return;
    }
    // ---- GEMM part: 8 rows/wave, scalar h operands ----
    int gb = blockIdx.x - histBlocks;
    for (int i = threadIdx.x; i < K * 64; i += 256) Ws[i] = W[i];
    __syncthreads();
    const int ROWS = 8;
    int wid = __builtin_amdgcn_readfirstlane((gb * 256 + (int)threadIdx.x) >> 6);
    int lane = threadIdx.x & 63;
    long row0 = (long)wid * ROWS;   // N % 8 == 0 -> no partial wave
    if (row0 >= N) return;
    const float* __restrict__ hr = h + row0 * K;   // wave-uniform base

    float acc[ROWS];
#pragma unroll
    for (int r = 0; r < ROWS; ++r) acc[r] = 0.0f;

    for (int k0 = 0; k0 < K; k0 += 4) {   // 4-wide k chunks bound SGPR pressure
        float wv[4];
#pragma unroll
        for (int j = 0; j < 4; ++j) wv[j] = Ws[(k0 + j) * 64 + lane];
#pragma unroll
        for (int r = 0; r < ROWS; ++r) {
#pragma unroll
            for (int j = 0; j < 4; ++j)
                acc[r] += hr[(size_t)r * K + k0 + j] * wv[j];   // uniform -> s_load
        }
    }

    __half* mo = m + row0 * 64 + lane;
#pragma unroll
    for (int r = 0; r < ROWS; ++r) mo[r * 64] = __float2half(acc[r]);
}

// ---------------- P2a: exclusive scan of each bucket row over NC chunks ----------------
__global__ __launch_bounds__(256) void scan_chunks_kernel(int* __restrict__ hist,
                                                          int* __restrict__ btot) {
    int b = blockIdx.x;
    int t = threadIdx.x;
    int* row = hist + b * NC;
    int v[4];
    int base = 4 * t;   // 4 elements/thread covers 1024 >= NC
#pragma unroll
    for (int u = 0; u < 4; ++u) v[u] = (base + u < NC) ? row[base + u] : 0;
    int tsum = v[0] + v[1] + v[2] + v[3];
    __shared__ int s[256];
    s[t] = tsum;
    __syncthreads();
    for (int d = 1; d < 256; d <<= 1) {
        int x = (t >= d) ? s[t - d] : 0;
        __syncthreads();
        s[t] += x;
        __syncthreads();
    }
    int run = s[t] - tsum;   // exclusive prefix of thread sums
    if (t == 255) btot[b] = s[255];
#pragma unroll
    for (int u = 0; u < 4; ++u) {
        if (base + u < NC) row[base + u] = run;
        run += v[u];
    }
}

// ---- exclusive scan of NB totals -> bases; also writes grand total at out[NB] ----
__global__ void scan_buckets_kernel(const int* __restrict__ tot, int* __restrict__ out) {
    __shared__ int s[512];
    int t = threadIdx.x;
    int v = (t < NB) ? tot[t] : 0;
    s[t] = v;
    __syncthreads();
    for (int d = 1; d < 512; d <<= 1) {
        int x = (t >= d) ? s[t - d] : 0;
        __syncthreads();
        s[t] += x;
        __syncthreads();
    }
    if (t < NB) out[t] = s[t] - v;
    if (t == NB - 1) out[NB] = s[t];   // grand total
}

// ---------------- P3: scatter edges into dst buckets (LDS ranks, no global atomics) ----
__global__ __launch_bounds__(256) void scatter_kernel(const int* __restrict__ src,
                                                      const int* __restrict__ dst,
                                                      const int* __restrict__ hist,
                                                      const int* __restrict__ bbase,
                                                      int* __restrict__ src_b,
                                                      int* __restrict__ dst_b, int E) {
    __shared__ int offs[NB];
    for (int b = threadIdx.x; b < NB; b += 256)
        offs[b] = hist[b * NC + (int)blockIdx.x] + bbase[b];
    __syncthreads();
    int e0 = blockIdx.x * CHUNK;
    int e1 = min(e0 + CHUNK, E);
    for (int e = e0 + threadIdx.x; e < e1; e += 256) {
        int d = dst[e], s = src[e];
        int pos = atomicAdd(&offs[d >> 8], 1);   // LDS atomic
        src_b[pos] = s;
        dst_b[pos] = d;
    }
}

// ---- bucket_prep: degree count + PADDED in-bucket rowptr offsets + dinv (+gcnt) ----
__global__ __launch_bounds__(256) void bucket_prep_kernel(const int* __restrict__ dst_b,
                                                          const int* __restrict__ bbase,
                                                          const int* __restrict__ btot,
                                                          int* __restrict__ rowptr,
                                                          int* __restrict__ pbt,
                                                          float* __restrict__ dinv,
                                                          const int* __restrict__ batch,
                                                          int* __restrict__ gcnt, int N) {
    if ((int)blockIdx.x == NB) {   // per-graph node counts via binary search
        int g = threadIdx.x;
        if (g >= NGRAPH) return;
        auto lb = [&](int v) {
            int lo = 0, hi = N;
            while (lo < hi) {
                int mid = (lo + hi) >> 1;
                if (batch[mid] < v) lo = mid + 1; else hi = mid;
            }
            return lo;
        };
        gcnt[g] = lb(g + 1) - lb(g);
        return;
    }
    __shared__ int c256[256];
    __shared__ int s[256];
    int t = threadIdx.x;
    c256[t] = 0;
    __syncthreads();
    int lo = bbase[blockIdx.x], n = btot[blockIdx.x];
    for (int e = lo + t; e < lo + n; e += 256) atomicAdd(&c256[dst_b[e] & 255], 1);
    __syncthreads();
    int cnt = c256[t];
    int pcnt = (cnt + 7) & ~7;   // pad to multiple of 8
    s[t] = pcnt;
    __syncthreads();
    for (int d = 1; d < 256; d <<= 1) {
        int x = (t >= d) ? s[t - d] : 0;
        __syncthreads();
        s[t] += x;
        __syncthreads();
    }
    int node = blockIdx.x * 256 + t;
    if (node < N) {
        rowptr[node] = s[t] - pcnt;                   // in-bucket padded offset (abs later)
        dinv[node] = 1.0f / sqrtf((float)(cnt + 1));  // +1 self-loop (real degree)
    }
    if (t == 255) pbt[blockIdx.x] = s[255];           // padded bucket total
}

// ---- rowptr fixup: add padded bucket base; set rowptr[N] = grand total ----
__global__ void rowptr_fix_kernel(int* __restrict__ rowptr, const int* __restrict__ pbbase,
                                  int N) {
    int i = blockIdx.x * 256 + threadIdx.x;
    if (i < N) rowptr[i] += pbbase[i >> 8];
    if (i == 0) rowptr[N] = pbbase[NB];
}

// ---------------- bucket_fill: padded CSR (col only), LDS ranks; pad -> N ----------------
__global__ __launch_bounds__(256) void bucket_fill_kernel(const int* __restrict__ src_b,
                                                          const int* __restrict__ dst_b,
                                                          const int* __restrict__ bbase,
                                                          const int* __restrict__ btot,
                                                          const int* __restrict__ rowptr,
                                                          int* __restrict__ col, int N) {
    __shared__ int f256[256];
    __shared__ int rp[256];
    int t = threadIdx.x;
    f256[t] = 0;
    int node = blockIdx.x * 256 + t;
    rp[t] = (node < N) ? rowptr[node] : 0;
    __syncthreads();
    int lo = bbase[blockIdx.x], n = btot[blockIdx.x];
    for (int e = lo + t; e < lo + n; e += 256) {
        int d = dst_b[e], sv = src_b[e];
        int li = d & 255;
        int slot = atomicAdd(&f256[li], 1);   // LDS atomic
        col[rp[li] + slot] = sv;
    }
    __syncthreads();
    if (node < N) {   // fill padding with zero-row index N
        int c = f256[t];
        int pc = (c + 7) & ~7;
        int base = rp[t];
        for (int p = c; p < pc; ++p) col[base + p] = N;
    }
}

// ---------------- scale m rows by dinv + zero the pad row N ----------------
__global__ __launch_bounds__(256) void scale_m_kernel(__half* __restrict__ m,
                                                      __half* __restrict__ other,
                                                      const float* __restrict__ dinv, int N) {
    if (blockIdx.x == 0 && threadIdx.x < 64) {   // zero row N of both layer buffers
        m[(size_t)N * 64 + threadIdx.x] = __float2half(0.0f);
        other[(size_t)N * 64 + threadIdx.x] = __float2half(0.0f);
    }
    int tot = N * 32;   // half2 elements
    __half2* m2 = (__half2*)m;
    for (int idx = blockIdx.x * 256 + threadIdx.x; idx < tot; idx += gridDim.x * 256) {
        float d = dinv[idx >> 5];
        float2 f = __half22float2(m2[idx]);
        f.x *= d;
        f.y *= d;
        m2[idx] = __float22half2_rn(f);
    }
}

// Pair gather over contiguous padded ranges [r0,mid)->A, [mid,r1)->B.
// r0, mid, r1 all multiples of 8 -> 8-blocks never straddle the split; the
// A/B choice per block is wave-uniform (SGPR compare). col indices are scalar
// (s_load) -> gathers use SGPR base addressing, ~zero VALU per load.
__device__ __forceinline__ void pair_gather(const __half* __restrict__ h,
                                            const int* __restrict__ col,
                                            int r0, int mid, int r1, int lane,
                                            float& aA, float& aB) {
    int n = r1 - r0;
    int e = 0;
    for (; e + 16 <= n; e += 16) {
        int base = r0 + e;
        int c[16];
        float v[16];
#pragma unroll
        for (int u = 0; u < 16; ++u) c[u] = col[base + u];
#pragma unroll
        for (int u = 0; u < 16; ++u) v[u] = __half2float(h[(size_t)c[u] * 64 + lane]);
        float s0 = ((v[0] + v[1]) + (v[2] + v[3])) + ((v[4] + v[5]) + (v[6] + v[7]));
        float s1 = ((v[8] + v[9]) + (v[10] + v[11])) + ((v[12] + v[13]) + (v[14] + v[15]));
        bool b0 = (base < mid);       // uniform per 8-block
        bool b1 = (base + 8 < mid);
        aA += b0 ? s0 : 0.0f;
        aB += b0 ? 0.0f : s0;
        aA += b1 ? s1 : 0.0f;
        aB += b1 ? 0.0f : s1;
    }
    if (e + 8 <= n) {   // remainder is exactly 0 or 8
        int base = r0 + e;
        int c[8];
        float v[8];
#pragma unroll
        for (int u = 0; u < 8; ++u) c[u] = col[base + u];
#pragma unroll
        for (int u = 0; u < 8; ++u) v[u] = __half2float(h[(size_t)c[u] * 64 + lane]);
        float s0 = ((v[0] + v[1]) + (v[2] + v[3])) + ((v[4] + v[5]) + (v[6] + v[7]));
        bool b0 = (base < mid);
        aA += b0 ? s0 : 0.0f;
        aB += b0 ? 0.0f : s0;
    }
}

// ---------------- layer-0 aggregation (2 nodes/wave, m pre-scaled) ----------------
__global__ __launch_bounds__(256) void agg0_kernel(const __half* __restrict__ m,
                                                   const int* __restrict__ rowptr,
                                                   const int* __restrict__ col,
                                                   const float* __restrict__ dinv,
                                                   const float* __restrict__ bias,
                                                   __half* __restrict__ hout, int N) {
    int wid = __builtin_amdgcn_readfirstlane((blockIdx.x * 256 + threadIdx.x) >> 6);
    int lane = threadIdx.x & 63;
    int nodeA = wid * 2;
    int nodeB = nodeA + 1;   // N even
    if (nodeA >= N) return;
    int r0 = rowptr[nodeA];
    int mid = rowptr[nodeB];
    int r1 = rowptr[nodeB + 1];
    float diA = dinv[nodeA], diB = dinv[nodeB];
    float aA = __half2float(m[(size_t)nodeA * 64 + lane]);   // self (pre-scaled)
    float aB = __half2float(m[(size_t)nodeB * 64 + lane]);
    pair_gather(m, col, r0, mid, r1, lane, aA, aB);
    float bv = bias[lane];
    float hA = fmaxf(diA * aA + bv, 0.0f);
    float hB = fmaxf(diB * aB + bv, 0.0f);
    hout[(size_t)nodeA * 64 + lane] = __float2half(diA * hA);   // pre-scaled out
    hout[(size_t)nodeB * 64 + lane] = __float2half(diB * hB);
}

// ---------------- fused layer, 2 nodes/wave: h' = relu((A h) W + b) ----------------
__global__ __launch_bounds__(256) void fused_kernel(const __half* __restrict__ h,
                                                    const int* __restrict__ rowptr,
                                                    const int* __restrict__ col,
                                                    const float* __restrict__ dinv,
                                                    const float* __restrict__ W,
                                                    const float* __restrict__ bias,
                                                    __half* __restrict__ hout, int N,
                                                    int scaleOut) {
    __shared__ float Ws[64 * 64];
    {
        const float4* W4 = (const float4*)W;
        float4* Ws4 = (float4*)Ws;
        for (int i = threadIdx.x; i < 64 * 16; i += 256) Ws4[i] = W4[i];
    }

    int wid = __builtin_amdgcn_readfirstlane((blockIdx.x * 256 + threadIdx.x) >> 6);
    int lane = threadIdx.x & 63;
    int nodeA = wid * 2;
    int nodeB = nodeA + 1;   // N even
    bool act = (nodeA < N);
    float gA = 0.0f, gB = 0.0f;
    float diA = 0.0f, diB = 0.0f;

    if (act) {
        int r0 = rowptr[nodeA];
        int mid = rowptr[nodeB];
        int r1 = rowptr[nodeB + 1];
        diA = dinv[nodeA];
        diB = dinv[nodeB];
        float aA = __half2float(h[(size_t)nodeA * 64 + lane]);   // self (pre-scaled)
        float aB = __half2float(h[(size_t)nodeB * 64 + lane]);
        pair_gather(h, col, r0, mid, r1, lane, aA, aB);
        gA = diA * aA;
        gB = diB * aB;
    }

    __syncthreads();   // W staging visible; all waves arrive

    if (act) {
        float bv = bias[lane];
        float accA = bv, accB = bv;
#pragma unroll
        for (int k = 0; k < 64; ++k) {
            float wv = Ws[k * 64 + lane];
            unsigned ga = __builtin_amdgcn_readlane(__float_as_uint(gA), k);
            unsigned gb = __builtin_amdgcn_readlane(__float_as_uint(gB), k);
            accA += __uint_as_float(ga) * wv;
            accB += __uint_as_float(gb) * wv;
        }
        accA = fmaxf(accA, 0.0f);
        accB = fmaxf(accB, 0.0f);
        if (scaleOut) { accA *= diA; accB *= diB; }   // pre-scale for next layer
        hout[(size_t)nodeA * 64 + lane] = __float2half(accA);
        hout[(size_t)nodeB * 64 + lane] = __float2half(accB);
    }
}

// ---------------- pooling: segment sum over sorted batch ids ----------------
__global__ __launch_bounds__(256) void pool_kernel(const __half* __restrict__ h,
                                                   const int* __restrict__ batch,
                                                   float* __restrict__ gpool, int N) {
    const int NPW = 32;  // nodes per wave
    int wid = (blockIdx.x * 256 + threadIdx.x) >> 6;
    int lane = threadIdx.x & 63;
    int i0 = wid * NPW;
    if (i0 >= N) return;
    int i1 = min(i0 + NPW, N);
    int curg = batch[i0];
    float acc = 0.0f;
    for (int i = i0; i < i1; ++i) {
        int g = batch[i];
        if (g != curg) {
            atomicAdd(&gpool[curg * 64 + lane], acc);
            acc = 0.0f;
            curg = g;
        }
        acc += __half2float(h[(size_t)i * 64 + lane]);
    }
    atomicAdd(&gpool[curg * 64 + lane], acc);
}

// ---------------- final: out = (gpool/count) @ Wlin + blin ----------------
__global__ void final_kernel(const float* __restrict__ gpool, const int* __restrict__ gcnt,
                             const float* __restrict__ Wlin, const float* __restrict__ blin,
                             float* __restrict__ out) {
    int t = threadIdx.x;
    if (t >= NGRAPH * COUT) return;
    int g = t / COUT, o = t - g * COUT;
    float c = (float)gcnt[g];
    if (c < 1.0f) c = 1.0f;
    float s = 0.0f;
    for (int k = 0; k < 64; ++k) s += gpool[g * 64 + k] * Wlin[k * COUT + o];
    out[t] = s / c + blin[o];
}

extern "C" void kernel_launch(void* const* d_in, const int* in_sizes, int n_in,
                              void* d_out, int out_size, void* d_ws, size_t ws_size,
                              hipStream_t stream) {
    const float* x    = (const float*)d_in[0];
    const int*   ei   = (const int*)d_in[1];
    const int*   batch= (const int*)d_in[2];
    const float* W0   = (const float*)d_in[3];
    const float* b0   = (const float*)d_in[4];
    const float* Ws   = (const float*)d_in[5];
    const float* bs   = (const float*)d_in[6];
    const float* Wlin = (const float*)d_in[7];
    const float* blin = (const float*)d_in[8];
    float* out = (float*)d_out;

    const int N = NNODES, E = NEDGES;
    const int* srcp = ei;          // edge_index[0]
    const int* dstp = ei + E;      // edge_index[1]

    char* w = (char*)d_ws;
    float* gpool  = (float*)w; w += (size_t)NGRAPH * 64 * 4;
    size_t zero_bytes = (size_t)(w - (char*)d_ws);   // only gpool needs zeroing
    int*   gcnt   = (int*)w;   w += (size_t)NGRAPH * 4;
    float* dinv   = (float*)w; w += (size_t)N * 4;
    int*   rowptr = (int*)w;   w += (size_t)(N + 1) * 4;
    int*   hist   = (int*)w;   w += (size_t)NB * NC * 4;
    int*   btot   = (int*)w;   w += (size_t)NB * 4;
    int*   bbase  = (int*)w;   w += (size_t)(NB + 1) * 4;
    int*   pbt    = (int*)w;   w += (size_t)NB * 4;
    int*   pbbase = (int*)w;   w += (size_t)(NB + 1) * 4;
    int*   src_b  = (int*)w;   w += (size_t)E * 4;
    int*   dst_b  = (int*)w;   w += (size_t)E * 4;
    int*   col    = (int*)w;   w += ((size_t)E + 8 * N) * 4;   // padded CSR
    __half* bufA  = (__half*)w; w += (size_t)(N + 1) * 64 * 2;  // +zero row N
    __half* bufB  = (__half*)w; w += (size_t)(N + 1) * 64 * 2;

    hipMemsetAsync(d_ws, 0, zero_bytes, stream);

    int nblocks = (N + 255) / 256;       // 391
    int gemmblocks = (N + 31) / 32;      // 3125: 8 rows/wave, 4 waves/block

    // P1 histogram + layer-0 GEMM co-scheduled (independent)
    hist_gemm_kernel<128><<<NC + gemmblocks, 256, 0, stream>>>(
        dstp, hist, E, x, W0, bufB, N, NC);
    scan_chunks_kernel<<<NB, 256, 0, stream>>>(hist, btot);
    scan_buckets_kernel<<<1, 512, 0, stream>>>(btot, bbase);
    scatter_kernel<<<NC, 256, 0, stream>>>(srcp, dstp, hist, bbase, src_b, dst_b, E);
    bucket_prep_kernel<<<NB + 1, 256, 0, stream>>>(dst_b, bbase, btot, rowptr, pbt, dinv,
                                                   batch, gcnt, N);
    scan_buckets_kernel<<<1, 512, 0, stream>>>(pbt, pbbase);
    rowptr_fix_kernel<<<nblocks, 256, 0, stream>>>(rowptr, pbbase, N);
    bucket_fill_kernel<<<NB, 256, 0, stream>>>(src_b, dst_b, bbase, btot, rowptr, col, N);
    scale_m_kernel<<<2048, 256, 0, stream>>>(bufB, bufA, dinv, N);

    int pairblocks = (N / 2 + 3) / 4;     // 2 nodes/wave, 4 waves/block

    agg0_kernel<<<pairblocks, 256, 0, stream>>>(bufB, rowptr, col, dinv, b0, bufA, N);

    // layers 1..9 fused: h' = relu((A h) W + b); rows pre-scaled except the last
    __half* hin = bufA;
    __half* hout = bufB;
    for (int l = 0; l < NSTACK; ++l) {
        int scaleOut = (l < NSTACK - 1) ? 1 : 0;
        fused_kernel<<<pairblocks, 256, 0, stream>>>(hin, rowptr, col, dinv,
                                                     Ws + (size_t)l * 64 * 64,
                                                     bs + (size_t)l * 64, hout, N,
                                                     scaleOut);
        __half* t = hin; hin = hout; hout = t;
    }
    // final h is in `hin` after the swap

    int pwaves = (N + 31) / 32;
    int pblocks = (pwaves + 3) / 4;
    pool_kernel<<<pblocks, 256, 0, stream>>>(hin, batch, gpool, N);
    final_kernel<<<1, 896, 0, stream>>>(gpool, gcnt, Wlin, blin, out);
}

// Round 16
// 685.860 us; speedup vs baseline: 1.0119x; 1.0119x over previous
//
#include <hip/hip_runtime.h>
#include <hip/hip_fp16.h>

#define NNODES 100000
#define NEDGES 1600000
#define NGRAPH 128
#define CIN 128
#define CH 64
#define COUT 7
#define NSTACK 9

#define NB 391      // buckets of 256 nodes: ceil(100000/256)
#define CHUNK 2048  // edges per histogram/scatter block
#define NC 782      // ceil(1600000/2048)

// ---------------- merged: P1 bucket histogram (LDS only) + layer-0 GEMM ----------------
// GEMM half uses per-lane vector loads of h + readlane broadcast (2 VALU/FMA).
// NOTE: s_load-based uniform h reads were tried (r15) and regressed: scalar
// cache path re-fetches x from HBM (FETCH 28->53MB) and scalar-wait chains
// stall the wave (VALUBusy 66->21%). Keep the readlane form.
template <int K>
__global__ __launch_bounds__(256) void hist_gemm_kernel(const int* __restrict__ dst,
                                                        int* __restrict__ hist, int E,
                                                        const float* __restrict__ h,
                                                        const float* __restrict__ W,
                                                        __half* __restrict__ m, int N,
                                                        int histBlocks) {
    __shared__ float Ws[K * 64];
    __shared__ int lh[NB];
    if (blockIdx.x < (unsigned)histBlocks) {
        for (int i = threadIdx.x; i < NB; i += 256) lh[i] = 0;
        __syncthreads();
        int e0 = blockIdx.x * CHUNK;
        int e1 = min(e0 + CHUNK, E);
        for (int e = e0 + threadIdx.x; e < e1; e += 256)
            atomicAdd(&lh[dst[e] >> 8], 1);   // LDS atomic
        __syncthreads();
        for (int i = threadIdx.x; i < NB; i += 256) hist[i * NC + (int)blockIdx.x] = lh[i];
        return;
    }
    // ---- GEMM part: 8 rows/wave ----
    int gb = blockIdx.x - histBlocks;
    for (int i = threadIdx.x; i < K * 64; i += 256) Ws[i] = W[i];
    __syncthreads();
    const int ROWS = 8;
    int wid = (gb * 256 + (int)threadIdx.x) >> 6;
    int lane = threadIdx.x & 63;
    long row0 = (long)wid * ROWS;
    if (row0 >= N) return;
    const float* hr = h + row0 * K + lane;

    float hv[ROWS][K / 64];
#pragma unroll
    for (int r = 0; r < ROWS; ++r)
#pragma unroll
        for (int q = 0; q < K / 64; ++q)
            hv[r][q] = hr[(size_t)r * K + q * 64];

    float acc[ROWS];
#pragma unroll
    for (int r = 0; r < ROWS; ++r) acc[r] = 0.0f;

#pragma unroll
    for (int k = 0; k < K; ++k) {
        float wv = Ws[k * 64 + lane];
#pragma unroll
        for (int r = 0; r < ROWS; ++r) {
            unsigned hb = __builtin_amdgcn_readlane(__float_as_uint(hv[r][k >> 6]), k & 63);
            acc[r] += __uint_as_float(hb) * wv;
        }
    }

    __half* mo = m + row0 * 64 + lane;
#pragma unroll
    for (int r = 0; r < ROWS; ++r) mo[r * 64] = __float2half(acc[r]);
}

// ---------------- P2a: exclusive scan of each bucket row over NC chunks ----------------
__global__ __launch_bounds__(256) void scan_chunks_kernel(int* __restrict__ hist,
                                                          int* __restrict__ btot) {
    int b = blockIdx.x;
    int t = threadIdx.x;
    int* row = hist + b * NC;
    int v[4];
    int base = 4 * t;   // 4 elements/thread covers 1024 >= NC
#pragma unroll
    for (int u = 0; u < 4; ++u) v[u] = (base + u < NC) ? row[base + u] : 0;
    int tsum = v[0] + v[1] + v[2] + v[3];
    __shared__ int s[256];
    s[t] = tsum;
    __syncthreads();
    for (int d = 1; d < 256; d <<= 1) {
        int x = (t >= d) ? s[t - d] : 0;
        __syncthreads();
        s[t] += x;
        __syncthreads();
    }
    int run = s[t] - tsum;   // exclusive prefix of thread sums
    if (t == 255) btot[b] = s[255];
#pragma unroll
    for (int u = 0; u < 4; ++u) {
        if (base + u < NC) row[base + u] = run;
        run += v[u];
    }
}

// ---- exclusive scan of NB totals -> bases; also writes grand total at out[NB] ----
__global__ void scan_buckets_kernel(const int* __restrict__ tot, int* __restrict__ out) {
    __shared__ int s[512];
    int t = threadIdx.x;
    int v = (t < NB) ? tot[t] : 0;
    s[t] = v;
    __syncthreads();
    for (int d = 1; d < 512; d <<= 1) {
        int x = (t >= d) ? s[t - d] : 0;
        __syncthreads();
        s[t] += x;
        __syncthreads();
    }
    if (t < NB) out[t] = s[t] - v;
    if (t == NB - 1) out[NB] = s[t];   // grand total
}

// ---------------- P3: scatter edges into dst buckets (LDS ranks, no global atomics) ----
__global__ __launch_bounds__(256) void scatter_kernel(const int* __restrict__ src,
                                                      const int* __restrict__ dst,
                                                      const int* __restrict__ hist,
                                                      const int* __restrict__ bbase,
                                                      int* __restrict__ src_b,
                                                      int* __restrict__ dst_b, int E) {
    __shared__ int offs[NB];
    for (int b = threadIdx.x; b < NB; b += 256)
        offs[b] = hist[b * NC + (int)blockIdx.x] + bbase[b];
    __syncthreads();
    int e0 = blockIdx.x * CHUNK;
    int e1 = min(e0 + CHUNK, E);
    for (int e = e0 + threadIdx.x; e < e1; e += 256) {
        int d = dst[e], s = src[e];
        int pos = atomicAdd(&offs[d >> 8], 1);   // LDS atomic
        src_b[pos] = s;
        dst_b[pos] = d;
    }
}

// ---- bucket_prep: degree count + PADDED in-bucket rowptr offsets + dinv (+gcnt) ----
__global__ __launch_bounds__(256) void bucket_prep_kernel(const int* __restrict__ dst_b,
                                                          const int* __restrict__ bbase,
                                                          const int* __restrict__ btot,
                                                          int* __restrict__ rowptr,
                                                          int* __restrict__ pbt,
                                                          float* __restrict__ dinv,
                                                          const int* __restrict__ batch,
                                                          int* __restrict__ gcnt, int N) {
    if ((int)blockIdx.x == NB) {   // per-graph node counts via binary search
        int g = threadIdx.x;
        if (g >= NGRAPH) return;
        auto lb = [&](int v) {
            int lo = 0, hi = N;
            while (lo < hi) {
                int mid = (lo + hi) >> 1;
                if (batch[mid] < v) lo = mid + 1; else hi = mid;
            }
            return lo;
        };
        gcnt[g] = lb(g + 1) - lb(g);
        return;
    }
    __shared__ int c256[256];
    __shared__ int s[256];
    int t = threadIdx.x;
    c256[t] = 0;
    __syncthreads();
    int lo = bbase[blockIdx.x], n = btot[blockIdx.x];
    for (int e = lo + t; e < lo + n; e += 256) atomicAdd(&c256[dst_b[e] & 255], 1);
    __syncthreads();
    int cnt = c256[t];
    int pcnt = (cnt + 7) & ~7;   // pad to multiple of 8
    s[t] = pcnt;
    __syncthreads();
    for (int d = 1; d < 256; d <<= 1) {
        int x = (t >= d) ? s[t - d] : 0;
        __syncthreads();
        s[t] += x;
        __syncthreads();
    }
    int node = blockIdx.x * 256 + t;
    if (node < N) {
        rowptr[node] = s[t] - pcnt;                   // in-bucket padded offset (abs later)
        dinv[node] = 1.0f / sqrtf((float)(cnt + 1));  // +1 self-loop (real degree)
    }
    if (t == 255) pbt[blockIdx.x] = s[255];           // padded bucket total
}

// ---- rowptr fixup: add padded bucket base; set rowptr[N] = grand total ----
__global__ void rowptr_fix_kernel(int* __restrict__ rowptr, const int* __restrict__ pbbase,
                                  int N) {
    int i = blockIdx.x * 256 + threadIdx.x;
    if (i < N) rowptr[i] += pbbase[i >> 8];
    if (i == 0) rowptr[N] = pbbase[NB];
}

// ---------------- bucket_fill: padded CSR (col only), LDS ranks; pad -> N ----------------
__global__ __launch_bounds__(256) void bucket_fill_kernel(const int* __restrict__ src_b,
                                                          const int* __restrict__ dst_b,
                                                          const int* __restrict__ bbase,
                                                          const int* __restrict__ btot,
                                                          const int* __restrict__ rowptr,
                                                          int* __restrict__ col, int N) {
    __shared__ int f256[256];
    __shared__ int rp[256];
    int t = threadIdx.x;
    f256[t] = 0;
    int node = blockIdx.x * 256 + t;
    rp[t] = (node < N) ? rowptr[node] : 0;
    __syncthreads();
    int lo = bbase[blockIdx.x], n = btot[blockIdx.x];
    for (int e = lo + t; e < lo + n; e += 256) {
        int d = dst_b[e], sv = src_b[e];
        int li = d & 255;
        int slot = atomicAdd(&f256[li], 1);   // LDS atomic
        col[rp[li] + slot] = sv;
    }
    __syncthreads();
    if (node < N) {   // fill padding with zero-row index N
        int c = f256[t];
        int pc = (c + 7) & ~7;
        int base = rp[t];
        for (int p = c; p < pc; ++p) col[base + p] = N;
    }
}

// ---------------- scale m rows by dinv + zero the pad row N ----------------
__global__ __launch_bounds__(256) void scale_m_kernel(__half* __restrict__ m,
                                                      __half* __restrict__ other,
                                                      const float* __restrict__ dinv, int N) {
    if (blockIdx.x == 0 && threadIdx.x < 64) {   // zero row N of both layer buffers
        m[(size_t)N * 64 + threadIdx.x] = __float2half(0.0f);
        other[(size_t)N * 64 + threadIdx.x] = __float2half(0.0f);
    }
    int tot = N * 32;   // half2 elements
    __half2* m2 = (__half2*)m;
    for (int idx = blockIdx.x * 256 + threadIdx.x; idx < tot; idx += gridDim.x * 256) {
        float d = dinv[idx >> 5];
        float2 f = __half22float2(m2[idx]);
        f.x *= d;
        f.y *= d;
        m2[idx] = __float22half2_rn(f);
    }
}

// Pair gather over contiguous padded ranges [r0,mid)->A, [mid,r1)->B.
// r0, mid, r1 all multiples of 8 -> 8-blocks never straddle the split; the
// A/B choice per block is wave-uniform (SGPR compare). col indices are scalar
// (s_load) -> gathers use SGPR base addressing, ~zero VALU per load.
__device__ __forceinline__ void pair_gather(const __half* __restrict__ h,
                                            const int* __restrict__ col,
                                            int r0, int mid, int r1, int lane,
                                            float& aA, float& aB) {
    int n = r1 - r0;
    int e = 0;
    for (; e + 16 <= n; e += 16) {
        int base = r0 + e;
        int c[16];
        float v[16];
#pragma unroll
        for (int u = 0; u < 16; ++u) c[u] = col[base + u];
#pragma unroll
        for (int u = 0; u < 16; ++u) v[u] = __half2float(h[(size_t)c[u] * 64 + lane]);
        float s0 = ((v[0] + v[1]) + (v[2] + v[3])) + ((v[4] + v[5]) + (v[6] + v[7]));
        float s1 = ((v[8] + v[9]) + (v[10] + v[11])) + ((v[12] + v[13]) + (v[14] + v[15]));
        bool b0 = (base < mid);       // uniform per 8-block
        bool b1 = (base + 8 < mid);
        aA += b0 ? s0 : 0.0f;
        aB += b0 ? 0.0f : s0;
        aA += b1 ? s1 : 0.0f;
        aB += b1 ? 0.0f : s1;
    }
    if (e + 8 <= n) {   // remainder is exactly 0 or 8
        int base = r0 + e;
        int c[8];
        float v[8];
#pragma unroll
        for (int u = 0; u < 8; ++u) c[u] = col[base + u];
#pragma unroll
        for (int u = 0; u < 8; ++u) v[u] = __half2float(h[(size_t)c[u] * 64 + lane]);
        float s0 = ((v[0] + v[1]) + (v[2] + v[3])) + ((v[4] + v[5]) + (v[6] + v[7]));
        bool b0 = (base < mid);
        aA += b0 ? s0 : 0.0f;
        aB += b0 ? 0.0f : s0;
    }
}

// ---------------- layer-0 aggregation (2 nodes/wave, m pre-scaled) ----------------
__global__ __launch_bounds__(256) void agg0_kernel(const __half* __restrict__ m,
                                                   const int* __restrict__ rowptr,
                                                   const int* __restrict__ col,
                                                   const float* __restrict__ dinv,
                                                   const float* __restrict__ bias,
                                                   __half* __restrict__ hout, int N) {
    int wid = __builtin_amdgcn_readfirstlane((blockIdx.x * 256 + threadIdx.x) >> 6);
    int lane = threadIdx.x & 63;
    int nodeA = wid * 2;
    int nodeB = nodeA + 1;   // N even
    if (nodeA >= N) return;
    int r0 = rowptr[nodeA];
    int mid = rowptr[nodeB];
    int r1 = rowptr[nodeB + 1];
    float diA = dinv[nodeA], diB = dinv[nodeB];
    float aA = __half2float(m[(size_t)nodeA * 64 + lane]);   // self (pre-scaled)
    float aB = __half2float(m[(size_t)nodeB * 64 + lane]);
    pair_gather(m, col, r0, mid, r1, lane, aA, aB);
    float bv = bias[lane];
    float hA = fmaxf(diA * aA + bv, 0.0f);
    float hB = fmaxf(diB * aB + bv, 0.0f);
    hout[(size_t)nodeA * 64 + lane] = __float2half(diA * hA);   // pre-scaled out
    hout[(size_t)nodeB * 64 + lane] = __float2half(diB * hB);
}

// ---------------- fused layer, 2 nodes/wave: h' = relu((A h) W + b) ----------------
__global__ __launch_bounds__(256) void fused_kernel(const __half* __restrict__ h,
                                                    const int* __restrict__ rowptr,
                                                    const int* __restrict__ col,
                                                    const float* __restrict__ dinv,
                                                    const float* __restrict__ W,
                                                    const float* __restrict__ bias,
                                                    __half* __restrict__ hout, int N,
                                                    int scaleOut) {
    __shared__ float Ws[64 * 64];
    {
        const float4* W4 = (const float4*)W;
        float4* Ws4 = (float4*)Ws;
        for (int i = threadIdx.x; i < 64 * 16; i += 256) Ws4[i] = W4[i];
    }

    int wid = __builtin_amdgcn_readfirstlane((blockIdx.x * 256 + threadIdx.x) >> 6);
    int lane = threadIdx.x & 63;
    int nodeA = wid * 2;
    int nodeB = nodeA + 1;   // N even
    bool act = (nodeA < N);
    float gA = 0.0f, gB = 0.0f;
    float diA = 0.0f, diB = 0.0f;

    if (act) {
        int r0 = rowptr[nodeA];
        int mid = rowptr[nodeB];
        int r1 = rowptr[nodeB + 1];
        diA = dinv[nodeA];
        diB = dinv[nodeB];
        float aA = __half2float(h[(size_t)nodeA * 64 + lane]);   // self (pre-scaled)
        float aB = __half2float(h[(size_t)nodeB * 64 + lane]);
        pair_gather(h, col, r0, mid, r1, lane, aA, aB);
        gA = diA * aA;
        gB = diB * aB;
    }

    __syncthreads();   // W staging visible; all waves arrive

    if (act) {
        float bv = bias[lane];
        float accA = bv, accB = bv;
#pragma unroll
        for (int k = 0; k < 64; ++k) {
            float wv = Ws[k * 64 + lane];
            unsigned ga = __builtin_amdgcn_readlane(__float_as_uint(gA), k);
            unsigned gb = __builtin_amdgcn_readlane(__float_as_uint(gB), k);
            accA += __uint_as_float(ga) * wv;
            accB += __uint_as_float(gb) * wv;
        }
        accA = fmaxf(accA, 0.0f);
        accB = fmaxf(accB, 0.0f);
        if (scaleOut) { accA *= diA; accB *= diB; }   // pre-scale for next layer
        hout[(size_t)nodeA * 64 + lane] = __float2half(accA);
        hout[(size_t)nodeB * 64 + lane] = __float2half(accB);
    }
}

// ---------------- pooling: segment sum over sorted batch ids ----------------
__global__ __launch_bounds__(256) void pool_kernel(const __half* __restrict__ h,
                                                   const int* __restrict__ batch,
                                                   float* __restrict__ gpool, int N) {
    const int NPW = 32;  // nodes per wave
    int wid = (blockIdx.x * 256 + threadIdx.x) >> 6;
    int lane = threadIdx.x & 63;
    int i0 = wid * NPW;
    if (i0 >= N) return;
    int i1 = min(i0 + NPW, N);
    int curg = batch[i0];
    float acc = 0.0f;
    for (int i = i0; i < i1; ++i) {
        int g = batch[i];
        if (g != curg) {
            atomicAdd(&gpool[curg * 64 + lane], acc);
            acc = 0.0f;
            curg = g;
        }
        acc += __half2float(h[(size_t)i * 64 + lane]);
    }
    atomicAdd(&gpool[curg * 64 + lane], acc);
}

// ---------------- final: out = (gpool/count) @ Wlin + blin ----------------
__global__ void final_kernel(const float* __restrict__ gpool, const int* __restrict__ gcnt,
                             const float* __restrict__ Wlin, const float* __restrict__ blin,
                             float* __restrict__ out) {
    int t = threadIdx.x;
    if (t >= NGRAPH * COUT) return;
    int g = t / COUT, o = t - g * COUT;
    float c = (float)gcnt[g];
    if (c < 1.0f) c = 1.0f;
    float s = 0.0f;
    for (int k = 0; k < 64; ++k) s += gpool[g * 64 + k] * Wlin[k * COUT + o];
    out[t] = s / c + blin[o];
}

extern "C" void kernel_launch(void* const* d_in, const int* in_sizes, int n_in,
                              void* d_out, int out_size, void* d_ws, size_t ws_size,
                              hipStream_t stream) {
    const float* x    = (const float*)d_in[0];
    const int*   ei   = (const int*)d_in[1];
    const int*   batch= (const int*)d_in[2];
    const float* W0   = (const float*)d_in[3];
    const float* b0   = (const float*)d_in[4];
    const float* Ws   = (const float*)d_in[5];
    const float* bs   = (const float*)d_in[6];
    const float* Wlin = (const float*)d_in[7];
    const float* blin = (const float*)d_in[8];
    float* out = (float*)d_out;

    const int N = NNODES, E = NEDGES;
    const int* srcp = ei;          // edge_index[0]
    const int* dstp = ei + E;      // edge_index[1]

    char* w = (char*)d_ws;
    float* gpool  = (float*)w; w += (size_t)NGRAPH * 64 * 4;
    size_t zero_bytes = (size_t)(w - (char*)d_ws);   // only gpool needs zeroing
    int*   gcnt   = (int*)w;   w += (size_t)NGRAPH * 4;
    float* dinv   = (float*)w; w += (size_t)N * 4;
    int*   rowptr = (int*)w;   w += (size_t)(N + 1) * 4;
    int*   hist   = (int*)w;   w += (size_t)NB * NC * 4;
    int*   btot   = (int*)w;   w += (size_t)NB * 4;
    int*   bbase  = (int*)w;   w += (size_t)(NB + 1) * 4;
    int*   pbt    = (int*)w;   w += (size_t)NB * 4;
    int*   pbbase = (int*)w;   w += (size_t)(NB + 1) * 4;
    int*   src_b  = (int*)w;   w += (size_t)E * 4;
    int*   dst_b  = (int*)w;   w += (size_t)E * 4;
    int*   col    = (int*)w;   w += ((size_t)E + 8 * N) * 4;   // padded CSR
    __half* bufA  = (__half*)w; w += (size_t)(N + 1) * 64 * 2;  // +zero row N
    __half* bufB  = (__half*)w; w += (size_t)(N + 1) * 64 * 2;

    hipMemsetAsync(d_ws, 0, zero_bytes, stream);

    int nblocks = (N + 255) / 256;       // 391
    int gemmblocks = (N + 31) / 32;      // 3125: 8 rows/wave, 4 waves/block

    // P1 histogram + layer-0 GEMM co-scheduled (independent)
    hist_gemm_kernel<128><<<NC + gemmblocks, 256, 0, stream>>>(
        dstp, hist, E, x, W0, bufB, N, NC);
    scan_chunks_kernel<<<NB, 256, 0, stream>>>(hist, btot);
    scan_buckets_kernel<<<1, 512, 0, stream>>>(btot, bbase);
    scatter_kernel<<<NC, 256, 0, stream>>>(srcp, dstp, hist, bbase, src_b, dst_b, E);
    bucket_prep_kernel<<<NB + 1, 256, 0, stream>>>(dst_b, bbase, btot, rowptr, pbt, dinv,
                                                   batch, gcnt, N);
    scan_buckets_kernel<<<1, 512, 0, stream>>>(pbt, pbbase);
    rowptr_fix_kernel<<<nblocks, 256, 0, stream>>>(rowptr, pbbase, N);
    bucket_fill_kernel<<<NB, 256, 0, stream>>>(src_b, dst_b, bbase, btot, rowptr, col, N);
    scale_m_kernel<<<2048, 256, 0, stream>>>(bufB, bufA, dinv, N);

    int pairblocks = (N / 2 + 3) / 4;     // 2 nodes/wave, 4 waves/block

    agg0_kernel<<<pairblocks, 256, 0, stream>>>(bufB, rowptr, col, dinv, b0, bufA, N);

    // layers 1..9 fused: h' = relu((A h) W + b); rows pre-scaled except the last
    __half* hin = bufA;
    __half* hout = bufB;
    for (int l = 0; l < NSTACK; ++l) {
        int scaleOut = (l < NSTACK - 1) ? 1 : 0;
        fused_kernel<<<pairblocks, 256, 0, stream>>>(hin, rowptr, col, dinv,
                                                     Ws + (size_t)l * 64 * 64,
                                                     bs + (size_t)l * 64, hout, N,
                                                     scaleOut);
        __half* t = hin; hin = hout; hout = t;
    }
    // final h is in `hin` after the swap

    int pwaves = (N + 31) / 32;
    int pblocks = (pwaves + 3) / 4;
    pool_kernel<<<pblocks, 256, 0, stream>>>(hin, batch, gpool, N);
    final_kernel<<<1, 896, 0, stream>>>(gpool, gcnt, Wlin, blin, out);
}

// Round 17
// 650.712 us; speedup vs baseline: 1.0665x; 1.0540x over previous
//
#include <hip/hip_runtime.h>
#include <hip/hip_fp16.h>

#define NNODES 100000
#define NEDGES 1600000
#define NGRAPH 128
#define CIN 128
#define CH 64
#define COUT 7
#define NSTACK 9

#define NB 391      // buckets of 256 nodes: ceil(100000/256)
#define CHUNK 2048  // edges per histogram/scatter block
#define NC 782      // ceil(1600000/2048)

typedef __attribute__((ext_vector_type(8))) short bf16x8;
typedef __attribute__((ext_vector_type(4))) float f32x4;

__device__ __forceinline__ unsigned short f2bf(float f) {
    unsigned u = __float_as_uint(f);
    return (unsigned short)((u + 0x7FFFu + ((u >> 16) & 1u)) >> 16);
}

// ---------------- merged: P1 bucket histogram (LDS only) + layer-0 MFMA GEMM ----------
// GEMM: m = x @ W0 via bf16-split MFMA (x_hi@W_hi + x_hi@W_lo + x_lo@W_hi):
// ~16-bit effective mantissa, MORE accurate than the fp16 store that follows.
// A-frags loaded straight from global (each kstep = exactly one 128B line per
// row, fully utilized), converted hi/lo in-register. W packed once per block
// into LDS in fragment order (lane-stride-16B reads, conflict-free).
// NOTE r15: s_load-based uniform h reads regressed (scalar cache re-fetch +
// scalar-wait stalls); r17: readlane VALU GEMM replaced by matrix pipe.
__global__ __launch_bounds__(256) void hist_gemm_kernel(const int* __restrict__ dst,
                                                        int* __restrict__ hist, int E,
                                                        const float* __restrict__ h,
                                                        const float* __restrict__ W,
                                                        __half* __restrict__ m, int N,
                                                        int histBlocks) {
    __shared__ alignas(16) char smem[32768 + 2048];
    if (blockIdx.x < (unsigned)histBlocks) {
        int* lh = (int*)smem;
        for (int i = threadIdx.x; i < NB; i += 256) lh[i] = 0;
        __syncthreads();
        int e0 = blockIdx.x * CHUNK;
        int e1 = min(e0 + CHUNK, E);
        for (int e = e0 + threadIdx.x; e < e1; e += 256)
            atomicAdd(&lh[dst[e] >> 8], 1);   // LDS atomic
        __syncthreads();
        for (int i = threadIdx.x; i < NB; i += 256) hist[i * NC + (int)blockIdx.x] = lh[i];
        return;
    }
    // ---- GEMM part: 64 rows/block, 16 rows/wave, MFMA 16x16x32 bf16 ----
    int gb = blockIdx.x - histBlocks;
    unsigned short* wf_hi = (unsigned short*)smem;        // [16 combos][64 lanes][8]
    unsigned short* wf_lo = wf_hi + 16 * 64 * 8;          // 16KB each
    int t = threadIdx.x;

    // pack W fragments: combo c=(kstep*4+ncol); lane l holds W[kstep*32+(l>>4)*8+i][ncol*16+(l&15)]
    {
        int c = t >> 4;            // 0..15
        int kstep = c >> 2, ncol = c & 3;
        int l0 = (t & 15) * 4;     // 4 lanes per thread
        for (int dl = 0; dl < 4; ++dl) {
            int l = l0 + dl;
            int kbase = kstep * 32 + (l >> 4) * 8;
            int n = ncol * 16 + (l & 15);
            for (int i = 0; i < 8; ++i) {
                float wv = W[(size_t)(kbase + i) * 64 + n];
                unsigned short hb = f2bf(wv);
                float hf = __uint_as_float(((unsigned)hb) << 16);
                wf_hi[((size_t)c * 64 + l) * 8 + i] = hb;
                wf_lo[((size_t)c * 64 + l) * 8 + i] = f2bf(wv - hf);
            }
        }
    }
    __syncthreads();

    int wave = t >> 6, lane = t & 63;
    long row0 = (long)gb * 64 + wave * 16;
    if (row0 >= N) return;   // N % 16 == 0 -> per-wave all-or-nothing; no barriers below

    long arow = row0 + (lane & 15);
    const float4* xr = (const float4*)(h + (size_t)arow * 128);
    int kg = lane >> 4;   // 0..3

    f32x4 zero = {0.0f, 0.0f, 0.0f, 0.0f};
    f32x4 acc[4];
    acc[0] = zero; acc[1] = zero; acc[2] = zero; acc[3] = zero;

#pragma unroll
    for (int s = 0; s < 4; ++s) {
        float4 p = xr[s * 8 + kg * 2];
        float4 q = xr[s * 8 + kg * 2 + 1];
        float xv[8] = {p.x, p.y, p.z, p.w, q.x, q.y, q.z, q.w};
        bf16x8 a_hi, a_lo;
#pragma unroll
        for (int i = 0; i < 8; ++i) {
            unsigned short hb = f2bf(xv[i]);
            a_hi[i] = (short)hb;
            a_lo[i] = (short)f2bf(xv[i] - __uint_as_float(((unsigned)hb) << 16));
        }
#pragma unroll
        for (int nc = 0; nc < 4; ++nc) {
            int c = s * 4 + nc;
            bf16x8 b_hi = *(const bf16x8*)(wf_hi + ((size_t)c * 64 + lane) * 8);
            bf16x8 b_lo = *(const bf16x8*)(wf_lo + ((size_t)c * 64 + lane) * 8);
            acc[nc] = __builtin_amdgcn_mfma_f32_16x16x32_bf16(a_hi, b_hi, acc[nc], 0, 0, 0);
            acc[nc] = __builtin_amdgcn_mfma_f32_16x16x32_bf16(a_hi, b_lo, acc[nc], 0, 0, 0);
            acc[nc] = __builtin_amdgcn_mfma_f32_16x16x32_bf16(a_lo, b_hi, acc[nc], 0, 0, 0);
        }
    }

    // store: D layout col=lane&15, row=(lane>>4)*4+reg  [verified m89/m91]
    int drow = (lane >> 4) * 4;
    int dcol = lane & 15;
#pragma unroll
    for (int nc = 0; nc < 4; ++nc)
#pragma unroll
        for (int r = 0; r < 4; ++r)
            m[(size_t)(row0 + drow + r) * 64 + nc * 16 + dcol] = __float2half(acc[nc][r]);
}

// ---------------- P2a: exclusive scan of each bucket row over NC chunks ----------------
__global__ __launch_bounds__(256) void scan_chunks_kernel(int* __restrict__ hist,
                                                          int* __restrict__ btot) {
    int b = blockIdx.x;
    int t = threadIdx.x;
    int* row = hist + b * NC;
    int v[4];
    int base = 4 * t;   // 4 elements/thread covers 1024 >= NC
#pragma unroll
    for (int u = 0; u < 4; ++u) v[u] = (base + u < NC) ? row[base + u] : 0;
    int tsum = v[0] + v[1] + v[2] + v[3];
    __shared__ int s[256];
    s[t] = tsum;
    __syncthreads();
    for (int d = 1; d < 256; d <<= 1) {
        int x = (t >= d) ? s[t - d] : 0;
        __syncthreads();
        s[t] += x;
        __syncthreads();
    }
    int run = s[t] - tsum;   // exclusive prefix of thread sums
    if (t == 255) btot[b] = s[255];
#pragma unroll
    for (int u = 0; u < 4; ++u) {
        if (base + u < NC) row[base + u] = run;
        run += v[u];
    }
}

// ---- exclusive scan of NB totals -> bases; also writes grand total at out[NB] ----
__global__ void scan_buckets_kernel(const int* __restrict__ tot, int* __restrict__ out) {
    __shared__ int s[512];
    int t = threadIdx.x;
    int v = (t < NB) ? tot[t] : 0;
    s[t] = v;
    __syncthreads();
    for (int d = 1; d < 512; d <<= 1) {
        int x = (t >= d) ? s[t - d] : 0;
        __syncthreads();
        s[t] += x;
        __syncthreads();
    }
    if (t < NB) out[t] = s[t] - v;
    if (t == NB - 1) out[NB] = s[t];   // grand total
}

// ---------------- P3: scatter edges into dst buckets (LDS ranks, no global atomics) ----
__global__ __launch_bounds__(256) void scatter_kernel(const int* __restrict__ src,
                                                      const int* __restrict__ dst,
                                                      const int* __restrict__ hist,
                                                      const int* __restrict__ bbase,
                                                      int* __restrict__ src_b,
                                                      int* __restrict__ dst_b, int E) {
    __shared__ int offs[NB];
    for (int b = threadIdx.x; b < NB; b += 256)
        offs[b] = hist[b * NC + (int)blockIdx.x] + bbase[b];
    __syncthreads();
    int e0 = blockIdx.x * CHUNK;
    int e1 = min(e0 + CHUNK, E);
    for (int e = e0 + threadIdx.x; e < e1; e += 256) {
        int d = dst[e], s = src[e];
        int pos = atomicAdd(&offs[d >> 8], 1);   // LDS atomic
        src_b[pos] = s;
        dst_b[pos] = d;
    }
}

// ---- bucket_prep: degree count + PADDED in-bucket rowptr offsets + dinv (+gcnt) ----
__global__ __launch_bounds__(256) void bucket_prep_kernel(const int* __restrict__ dst_b,
                                                          const int* __restrict__ bbase,
                                                          const int* __restrict__ btot,
                                                          int* __restrict__ rowptr,
                                                          int* __restrict__ pbt,
                                                          float* __restrict__ dinv,
                                                          const int* __restrict__ batch,
                                                          int* __restrict__ gcnt, int N) {
    if ((int)blockIdx.x == NB) {   // per-graph node counts via binary search
        int g = threadIdx.x;
        if (g >= NGRAPH) return;
        auto lb = [&](int v) {
            int lo = 0, hi = N;
            while (lo < hi) {
                int mid = (lo + hi) >> 1;
                if (batch[mid] < v) lo = mid + 1; else hi = mid;
            }
            return lo;
        };
        gcnt[g] = lb(g + 1) - lb(g);
        return;
    }
    __shared__ int c256[256];
    __shared__ int s[256];
    int t = threadIdx.x;
    c256[t] = 0;
    __syncthreads();
    int lo = bbase[blockIdx.x], n = btot[blockIdx.x];
    for (int e = lo + t; e < lo + n; e += 256) atomicAdd(&c256[dst_b[e] & 255], 1);
    __syncthreads();
    int cnt = c256[t];
    int pcnt = (cnt + 7) & ~7;   // pad to multiple of 8
    s[t] = pcnt;
    __syncthreads();
    for (int d = 1; d < 256; d <<= 1) {
        int x = (t >= d) ? s[t - d] : 0;
        __syncthreads();
        s[t] += x;
        __syncthreads();
    }
    int node = blockIdx.x * 256 + t;
    if (node < N) {
        rowptr[node] = s[t] - pcnt;                   // in-bucket padded offset (abs later)
        dinv[node] = 1.0f / sqrtf((float)(cnt + 1));  // +1 self-loop (real degree)
    }
    if (t == 255) pbt[blockIdx.x] = s[255];           // padded bucket total
}

// ---- rowptr fixup: add padded bucket base; set rowptr[N] = grand total ----
__global__ void rowptr_fix_kernel(int* __restrict__ rowptr, const int* __restrict__ pbbase,
                                  int N) {
    int i = blockIdx.x * 256 + threadIdx.x;
    if (i < N) rowptr[i] += pbbase[i >> 8];
    if (i == 0) rowptr[N] = pbbase[NB];
}

// ---------------- bucket_fill: padded CSR (col only), LDS ranks; pad -> N ----------------
__global__ __launch_bounds__(256) void bucket_fill_kernel(const int* __restrict__ src_b,
                                                          const int* __restrict__ dst_b,
                                                          const int* __restrict__ bbase,
                                                          const int* __restrict__ btot,
                                                          const int* __restrict__ rowptr,
                                                          int* __restrict__ col, int N) {
    __shared__ int f256[256];
    __shared__ int rp[256];
    int t = threadIdx.x;
    f256[t] = 0;
    int node = blockIdx.x * 256 + t;
    rp[t] = (node < N) ? rowptr[node] : 0;
    __syncthreads();
    int lo = bbase[blockIdx.x], n = btot[blockIdx.x];
    for (int e = lo + t; e < lo + n; e += 256) {
        int d = dst_b[e], sv = src_b[e];
        int li = d & 255;
        int slot = atomicAdd(&f256[li], 1);   // LDS atomic
        col[rp[li] + slot] = sv;
    }
    __syncthreads();
    if (node < N) {   // fill padding with zero-row index N
        int c = f256[t];
        int pc = (c + 7) & ~7;
        int base = rp[t];
        for (int p = c; p < pc; ++p) col[base + p] = N;
    }
}

// ---------------- scale m rows by dinv + zero the pad row N ----------------
__global__ __launch_bounds__(256) void scale_m_kernel(__half* __restrict__ m,
                                                      __half* __restrict__ other,
                                                      const float* __restrict__ dinv, int N) {
    if (blockIdx.x == 0 && threadIdx.x < 64) {   // zero row N of both layer buffers
        m[(size_t)N * 64 + threadIdx.x] = __float2half(0.0f);
        other[(size_t)N * 64 + threadIdx.x] = __float2half(0.0f);
    }
    int tot = N * 32;   // half2 elements
    __half2* m2 = (__half2*)m;
    for (int idx = blockIdx.x * 256 + threadIdx.x; idx < tot; idx += gridDim.x * 256) {
        float d = dinv[idx >> 5];
        float2 f = __half22float2(m2[idx]);
        f.x *= d;
        f.y *= d;
        m2[idx] = __float22half2_rn(f);
    }
}

// Pair gather over contiguous padded ranges [r0,mid)->A, [mid,r1)->B.
// r0, mid, r1 all multiples of 8 -> 8-blocks never straddle the split; the
// A/B choice per block is wave-uniform (SGPR compare). col indices are scalar
// (s_load) -> gathers use SGPR base addressing, ~zero VALU per load.
__device__ __forceinline__ void pair_gather(const __half* __restrict__ h,
                                            const int* __restrict__ col,
                                            int r0, int mid, int r1, int lane,
                                            float& aA, float& aB) {
    int n = r1 - r0;
    int e = 0;
    for (; e + 16 <= n; e += 16) {
        int base = r0 + e;
        int c[16];
        float v[16];
#pragma unroll
        for (int u = 0; u < 16; ++u) c[u] = col[base + u];
#pragma unroll
        for (int u = 0; u < 16; ++u) v[u] = __half2float(h[(size_t)c[u] * 64 + lane]);
        float s0 = ((v[0] + v[1]) + (v[2] + v[3])) + ((v[4] + v[5]) + (v[6] + v[7]));
        float s1 = ((v[8] + v[9]) + (v[10] + v[11])) + ((v[12] + v[13]) + (v[14] + v[15]));
        bool b0 = (base < mid);       // uniform per 8-block
        bool b1 = (base + 8 < mid);
        aA += b0 ? s0 : 0.0f;
        aB += b0 ? 0.0f : s0;
        aA += b1 ? s1 : 0.0f;
        aB += b1 ? 0.0f : s1;
    }
    if (e + 8 <= n) {   // remainder is exactly 0 or 8
        int base = r0 + e;
        int c[8];
        float v[8];
#pragma unroll
        for (int u = 0; u < 8; ++u) c[u] = col[base + u];
#pragma unroll
        for (int u = 0; u < 8; ++u) v[u] = __half2float(h[(size_t)c[u] * 64 + lane]);
        float s0 = ((v[0] + v[1]) + (v[2] + v[3])) + ((v[4] + v[5]) + (v[6] + v[7]));
        bool b0 = (base < mid);
        aA += b0 ? s0 : 0.0f;
        aB += b0 ? 0.0f : s0;
    }
}

// ---------------- layer-0 aggregation (2 nodes/wave, m pre-scaled) ----------------
__global__ __launch_bounds__(256) void agg0_kernel(const __half* __restrict__ m,
                                                   const int* __restrict__ rowptr,
                                                   const int* __restrict__ col,
                                                   const float* __restrict__ dinv,
                                                   const float* __restrict__ bias,
                                                   __half* __restrict__ hout, int N) {
    int wid = __builtin_amdgcn_readfirstlane((blockIdx.x * 256 + threadIdx.x) >> 6);
    int lane = threadIdx.x & 63;
    int nodeA = wid * 2;
    int nodeB = nodeA + 1;   // N even
    if (nodeA >= N) return;
    int r0 = rowptr[nodeA];
    int mid = rowptr[nodeB];
    int r1 = rowptr[nodeB + 1];
    float diA = dinv[nodeA], diB = dinv[nodeB];
    float aA = __half2float(m[(size_t)nodeA * 64 + lane]);   // self (pre-scaled)
    float aB = __half2float(m[(size_t)nodeB * 64 + lane]);
    pair_gather(m, col, r0, mid, r1, lane, aA, aB);
    float bv = bias[lane];
    float hA = fmaxf(diA * aA + bv, 0.0f);
    float hB = fmaxf(diB * aB + bv, 0.0f);
    hout[(size_t)nodeA * 64 + lane] = __float2half(diA * hA);   // pre-scaled out
    hout[(size_t)nodeB * 64 + lane] = __float2half(diB * hB);
}

// ---------------- fused layer, 2 nodes/wave: h' = relu((A h) W + b) ----------------
__global__ __launch_bounds__(256) void fused_kernel(const __half* __restrict__ h,
                                                    const int* __restrict__ rowptr,
                                                    const int* __restrict__ col,
                                                    const float* __restrict__ dinv,
                                                    const float* __restrict__ W,
                                                    const float* __restrict__ bias,
                                                    __half* __restrict__ hout, int N,
                                                    int scaleOut) {
    __shared__ float Ws[64 * 64];
    {
        const float4* W4 = (const float4*)W;
        float4* Ws4 = (float4*)Ws;
        for (int i = threadIdx.x; i < 64 * 16; i += 256) Ws4[i] = W4[i];
    }

    int wid = __builtin_amdgcn_readfirstlane((blockIdx.x * 256 + threadIdx.x) >> 6);
    int lane = threadIdx.x & 63;
    int nodeA = wid * 2;
    int nodeB = nodeA + 1;   // N even
    bool act = (nodeA < N);
    float gA = 0.0f, gB = 0.0f;
    float diA = 0.0f, diB = 0.0f;

    if (act) {
        int r0 = rowptr[nodeA];
        int mid = rowptr[nodeB];
        int r1 = rowptr[nodeB + 1];
        diA = dinv[nodeA];
        diB = dinv[nodeB];
        float aA = __half2float(h[(size_t)nodeA * 64 + lane]);   // self (pre-scaled)
        float aB = __half2float(h[(size_t)nodeB * 64 + lane]);
        pair_gather(h, col, r0, mid, r1, lane, aA, aB);
        gA = diA * aA;
        gB = diB * aB;
    }

    __syncthreads();   // W staging visible; all waves arrive

    if (act) {
        float bv = bias[lane];
        float accA = bv, accB = bv;
#pragma unroll
        for (int k = 0; k < 64; ++k) {
            float wv = Ws[k * 64 + lane];
            unsigned ga = __builtin_amdgcn_readlane(__float_as_uint(gA), k);
            unsigned gb = __builtin_amdgcn_readlane(__float_as_uint(gB), k);
            accA += __uint_as_float(ga) * wv;
            accB += __uint_as_float(gb) * wv;
        }
        accA = fmaxf(accA, 0.0f);
        accB = fmaxf(accB, 0.0f);
        if (scaleOut) { accA *= diA; accB *= diB; }   // pre-scale for next layer
        hout[(size_t)nodeA * 64 + lane] = __float2half(accA);
        hout[(size_t)nodeB * 64 + lane] = __float2half(accB);
    }
}

// ---------------- pooling: segment sum over sorted batch ids ----------------
__global__ __launch_bounds__(256) void pool_kernel(const __half* __restrict__ h,
                                                   const int* __restrict__ batch,
                                                   float* __restrict__ gpool, int N) {
    const int NPW = 32;  // nodes per wave
    int wid = (blockIdx.x * 256 + threadIdx.x) >> 6;
    int lane = threadIdx.x & 63;
    int i0 = wid * NPW;
    if (i0 >= N) return;
    int i1 = min(i0 + NPW, N);
    int curg = batch[i0];
    float acc = 0.0f;
    for (int i = i0; i < i1; ++i) {
        int g = batch[i];
        if (g != curg) {
            atomicAdd(&gpool[curg * 64 + lane], acc);
            acc = 0.0f;
            curg = g;
        }
        acc += __half2float(h[(size_t)i * 64 + lane]);
    }
    atomicAdd(&gpool[curg * 64 + lane], acc);
}

// ---------------- final: out = (gpool/count) @ Wlin + blin ----------------
__global__ void final_kernel(const float* __restrict__ gpool, const int* __restrict__ gcnt,
                             const float* __restrict__ Wlin, const float* __restrict__ blin,
                             float* __restrict__ out) {
    int t = threadIdx.x;
    if (t >= NGRAPH * COUT) return;
    int g = t / COUT, o = t - g * COUT;
    float c = (float)gcnt[g];
    if (c < 1.0f) c = 1.0f;
    float s = 0.0f;
    for (int k = 0; k < 64; ++k) s += gpool[g * 64 + k] * Wlin[k * COUT + o];
    out[t] = s / c + blin[o];
}

extern "C" void kernel_launch(void* const* d_in, const int* in_sizes, int n_in,
                              void* d_out, int out_size, void* d_ws, size_t ws_size,
                              hipStream_t stream) {
    const float* x    = (const float*)d_in[0];
    const int*   ei   = (const int*)d_in[1];
    const int*   batch= (const int*)d_in[2];
    const float* W0   = (const float*)d_in[3];
    const float* b0   = (const float*)d_in[4];
    const float* Ws   = (const float*)d_in[5];
    const float* bs   = (const float*)d_in[6];
    const float* Wlin = (const float*)d_in[7];
    const float* blin = (const float*)d_in[8];
    float* out = (float*)d_out;

    const int N = NNODES, E = NEDGES;
    const int* srcp = ei;          // edge_index[0]
    const int* dstp = ei + E;      // edge_index[1]

    char* w = (char*)d_ws;
    float* gpool  = (float*)w; w += (size_t)NGRAPH * 64 * 4;
    size_t zero_bytes = (size_t)(w - (char*)d_ws);   // only gpool needs zeroing
    int*   gcnt   = (int*)w;   w += (size_t)NGRAPH * 4;
    float* dinv   = (float*)w; w += (size_t)N * 4;
    int*   rowptr = (int*)w;   w += (size_t)(N + 1) * 4;
    int*   hist   = (int*)w;   w += (size_t)NB * NC * 4;
    int*   btot   = (int*)w;   w += (size_t)NB * 4;
    int*   bbase  = (int*)w;   w += (size_t)(NB + 1) * 4;
    int*   pbt    = (int*)w;   w += (size_t)NB * 4;
    int*   pbbase = (int*)w;   w += (size_t)(NB + 1) * 4;
    int*   src_b  = (int*)w;   w += (size_t)E * 4;
    int*   dst_b  = (int*)w;   w += (size_t)E * 4;
    int*   col    = (int*)w;   w += ((size_t)E + 8 * N) * 4;   // padded CSR
    __half* bufA  = (__half*)w; w += (size_t)(N + 1) * 64 * 2;  // +zero row N
    __half* bufB  = (__half*)w; w += (size_t)(N + 1) * 64 * 2;

    hipMemsetAsync(d_ws, 0, zero_bytes, stream);

    int nblocks = (N + 255) / 256;       // 391
    int gemmblocks = (N + 63) / 64;      // 1563: 16 rows/wave (MFMA), 4 waves/block

    // P1 histogram + layer-0 MFMA GEMM co-scheduled (independent)
    hist_gemm_kernel<<<NC + gemmblocks, 256, 0, stream>>>(
        dstp, hist, E, x, W0, bufB, N, NC);
    scan_chunks_kernel<<<NB, 256, 0, stream>>>(hist, btot);
    scan_buckets_kernel<<<1, 512, 0, stream>>>(btot, bbase);
    scatter_kernel<<<NC, 256, 0, stream>>>(srcp, dstp, hist, bbase, src_b, dst_b, E);
    bucket_prep_kernel<<<NB + 1, 256, 0, stream>>>(dst_b, bbase, btot, rowptr, pbt, dinv,
                                                   batch, gcnt, N);
    scan_buckets_kernel<<<1, 512, 0, stream>>>(pbt, pbbase);
    rowptr_fix_kernel<<<nblocks, 256, 0, stream>>>(rowptr, pbbase, N);
    bucket_fill_kernel<<<NB, 256, 0, stream>>>(src_b, dst_b, bbase, btot, rowptr, col, N);
    scale_m_kernel<<<2048, 256, 0, stream>>>(bufB, bufA, dinv, N);

    int pairblocks = (N / 2 + 3) / 4;     // 2 nodes/wave, 4 waves/block

    agg0_kernel<<<pairblocks, 256, 0, stream>>>(bufB, rowptr, col, dinv, b0, bufA, N);

    // layers 1..9 fused: h' = relu((A h) W + b); rows pre-scaled except the last
    __half* hin = bufA;
    __half* hout = bufB;
    for (int l = 0; l < NSTACK; ++l) {
        int scaleOut = (l < NSTACK - 1) ? 1 : 0;
        fused_kernel<<<pairblocks, 256, 0, stream>>>(hin, rowptr, col, dinv,
                                                     Ws + (size_t)l * 64 * 64,
                                                     bs + (size_t)l * 64, hout, N,
                                                     scaleOut);
        __half* t = hin; hin = hout; hout = t;
    }
    // final h is in `hin` after the swap

    int pwaves = (N + 31) / 32;
    int pblocks = (pwaves + 3) / 4;
    pool_kernel<<<pblocks, 256, 0, stream>>>(hin, batch, gpool, N);
    final_kernel<<<1, 896, 0, stream>>>(gpool, gcnt, Wlin, blin, out);
}

// Round 18
// 626.515 us; speedup vs baseline: 1.1077x; 1.0386x over previous
//
#include <hip/hip_runtime.h>
#include <hip/hip_fp16.h>

#define NNODES 100000
#define NEDGES 1600000
#define NGRAPH 128
#define CIN 128
#define CH 64
#define COUT 7
#define NSTACK 9

#define NB 391      // buckets of 256 nodes: ceil(100000/256)
#define CHUNK 2048  // edges per histogram/scatter block
#define NC 782      // ceil(1600000/2048)

typedef __attribute__((ext_vector_type(8))) short bf16x8;
typedef __attribute__((ext_vector_type(4))) float f32x4;

__device__ __forceinline__ unsigned short f2bf(float f) {
    unsigned u = __float_as_uint(f);
    return (unsigned short)((u + 0x7FFFu + ((u >> 16) & 1u)) >> 16);
}

// ---------------- merged: P1 bucket histogram (LDS only) + layer-0 MFMA GEMM ----------
// bf16-split MFMA (x_hi@W_hi + x_hi@W_lo + x_lo@W_hi): ~16-bit mantissa, more
// accurate than the fp16 store that follows. Fragment layouts validated r17.
__global__ __launch_bounds__(256) void hist_gemm_kernel(const int* __restrict__ dst,
                                                        int* __restrict__ hist, int E,
                                                        const float* __restrict__ h,
                                                        const float* __restrict__ W,
                                                        __half* __restrict__ m, int N,
                                                        int histBlocks) {
    __shared__ alignas(16) char smem[32768 + 2048];
    if (blockIdx.x < (unsigned)histBlocks) {
        int* lh = (int*)smem;
        for (int i = threadIdx.x; i < NB; i += 256) lh[i] = 0;
        __syncthreads();
        int e0 = blockIdx.x * CHUNK;
        int e1 = min(e0 + CHUNK, E);
        for (int e = e0 + threadIdx.x; e < e1; e += 256)
            atomicAdd(&lh[dst[e] >> 8], 1);   // LDS atomic
        __syncthreads();
        for (int i = threadIdx.x; i < NB; i += 256) hist[i * NC + (int)blockIdx.x] = lh[i];
        return;
    }
    // ---- GEMM part: 64 rows/block, 16 rows/wave, MFMA 16x16x32 bf16 ----
    int gb = blockIdx.x - histBlocks;
    unsigned short* wf_hi = (unsigned short*)smem;        // [16 combos][64 lanes][8]
    unsigned short* wf_lo = wf_hi + 16 * 64 * 8;          // 16KB each
    int t = threadIdx.x;

    {
        int c = t >> 4;            // 0..15
        int kstep = c >> 2, ncol = c & 3;
        int l0 = (t & 15) * 4;     // 4 lanes per thread
        for (int dl = 0; dl < 4; ++dl) {
            int l = l0 + dl;
            int kbase = kstep * 32 + (l >> 4) * 8;
            int n = ncol * 16 + (l & 15);
            for (int i = 0; i < 8; ++i) {
                float wv = W[(size_t)(kbase + i) * 64 + n];
                unsigned short hb = f2bf(wv);
                float hf = __uint_as_float(((unsigned)hb) << 16);
                wf_hi[((size_t)c * 64 + l) * 8 + i] = hb;
                wf_lo[((size_t)c * 64 + l) * 8 + i] = f2bf(wv - hf);
            }
        }
    }
    __syncthreads();

    int wave = t >> 6, lane = t & 63;
    long row0 = (long)gb * 64 + wave * 16;
    if (row0 >= N) return;

    long arow = row0 + (lane & 15);
    const float4* xr = (const float4*)(h + (size_t)arow * 128);
    int kg = lane >> 4;   // 0..3

    f32x4 zero = {0.0f, 0.0f, 0.0f, 0.0f};
    f32x4 acc[4];
    acc[0] = zero; acc[1] = zero; acc[2] = zero; acc[3] = zero;

#pragma unroll
    for (int s = 0; s < 4; ++s) {
        float4 p = xr[s * 8 + kg * 2];
        float4 q = xr[s * 8 + kg * 2 + 1];
        float xv[8] = {p.x, p.y, p.z, p.w, q.x, q.y, q.z, q.w};
        bf16x8 a_hi, a_lo;
#pragma unroll
        for (int i = 0; i < 8; ++i) {
            unsigned short hb = f2bf(xv[i]);
            a_hi[i] = (short)hb;
            a_lo[i] = (short)f2bf(xv[i] - __uint_as_float(((unsigned)hb) << 16));
        }
#pragma unroll
        for (int nc = 0; nc < 4; ++nc) {
            int c = s * 4 + nc;
            bf16x8 b_hi = *(const bf16x8*)(wf_hi + ((size_t)c * 64 + lane) * 8);
            bf16x8 b_lo = *(const bf16x8*)(wf_lo + ((size_t)c * 64 + lane) * 8);
            acc[nc] = __builtin_amdgcn_mfma_f32_16x16x32_bf16(a_hi, b_hi, acc[nc], 0, 0, 0);
            acc[nc] = __builtin_amdgcn_mfma_f32_16x16x32_bf16(a_hi, b_lo, acc[nc], 0, 0, 0);
            acc[nc] = __builtin_amdgcn_mfma_f32_16x16x32_bf16(a_lo, b_hi, acc[nc], 0, 0, 0);
        }
    }

    int drow = (lane >> 4) * 4;
    int dcol = lane & 15;
#pragma unroll
    for (int nc = 0; nc < 4; ++nc)
#pragma unroll
        for (int r = 0; r < 4; ++r)
            m[(size_t)(row0 + drow + r) * 64 + nc * 16 + dcol] = __float2half(acc[nc][r]);
}

// ---- pack all 9 stacked-layer W matrices into MFMA B-fragment order (bf16 hi/lo) ----
// Layout: wf[(l*8 + kstep*4 + ncol)*64 + lane][8]; value = W_l[kstep*32+(lane>>4)*8+i][ncol*16+(lane&15)]
__global__ void pack_wfrags_kernel(const float* __restrict__ Ws,
                                   unsigned short* __restrict__ wfh,
                                   unsigned short* __restrict__ wfl) {
    int b = blockIdx.x;        // 0..71 = l*8 + c
    int l = b >> 3, c = b & 7;
    int s = c >> 2, nc = c & 3;
    for (int v = threadIdx.x; v < 512; v += 256) {
        int L = v >> 3, i = v & 7;
        int k = s * 32 + (L >> 4) * 8 + i;
        int n = nc * 16 + (L & 15);
        float w = Ws[(size_t)l * 4096 + k * 64 + n];
        unsigned short hb = f2bf(w);
        float hf = __uint_as_float(((unsigned)hb) << 16);
        size_t idx = ((size_t)b * 64 + L) * 8 + i;
        wfh[idx] = hb;
        wfl[idx] = f2bf(w - hf);
    }
}

// ---------------- P2a: exclusive scan of each bucket row over NC chunks ----------------
__global__ __launch_bounds__(256) void scan_chunks_kernel(int* __restrict__ hist,
                                                          int* __restrict__ btot) {
    int b = blockIdx.x;
    int t = threadIdx.x;
    int* row = hist + b * NC;
    int v[4];
    int base = 4 * t;
#pragma unroll
    for (int u = 0; u < 4; ++u) v[u] = (base + u < NC) ? row[base + u] : 0;
    int tsum = v[0] + v[1] + v[2] + v[3];
    __shared__ int s[256];
    s[t] = tsum;
    __syncthreads();
    for (int d = 1; d < 256; d <<= 1) {
        int x = (t >= d) ? s[t - d] : 0;
        __syncthreads();
        s[t] += x;
        __syncthreads();
    }
    int run = s[t] - tsum;
    if (t == 255) btot[b] = s[255];
#pragma unroll
    for (int u = 0; u < 4; ++u) {
        if (base + u < NC) row[base + u] = run;
        run += v[u];
    }
}

// ---- exclusive scan of NB totals -> bases; also writes grand total at out[NB] ----
__global__ void scan_buckets_kernel(const int* __restrict__ tot, int* __restrict__ out) {
    __shared__ int s[512];
    int t = threadIdx.x;
    int v = (t < NB) ? tot[t] : 0;
    s[t] = v;
    __syncthreads();
    for (int d = 1; d < 512; d <<= 1) {
        int x = (t >= d) ? s[t - d] : 0;
        __syncthreads();
        s[t] += x;
        __syncthreads();
    }
    if (t < NB) out[t] = s[t] - v;
    if (t == NB - 1) out[NB] = s[t];
}

// ---------------- P3: scatter edges into dst buckets (LDS ranks, no global atomics) ----
__global__ __launch_bounds__(256) void scatter_kernel(const int* __restrict__ src,
                                                      const int* __restrict__ dst,
                                                      const int* __restrict__ hist,
                                                      const int* __restrict__ bbase,
                                                      int* __restrict__ src_b,
                                                      int* __restrict__ dst_b, int E) {
    __shared__ int offs[NB];
    for (int b = threadIdx.x; b < NB; b += 256)
        offs[b] = hist[b * NC + (int)blockIdx.x] + bbase[b];
    __syncthreads();
    int e0 = blockIdx.x * CHUNK;
    int e1 = min(e0 + CHUNK, E);
    for (int e = e0 + threadIdx.x; e < e1; e += 256) {
        int d = dst[e], s = src[e];
        int pos = atomicAdd(&offs[d >> 8], 1);   // LDS atomic
        src_b[pos] = s;
        dst_b[pos] = d;
    }
}

// ---- bucket_prep: degree count + PADDED in-bucket rowptr offsets + dinv (+gcnt) ----
__global__ __launch_bounds__(256) void bucket_prep_kernel(const int* __restrict__ dst_b,
                                                          const int* __restrict__ bbase,
                                                          const int* __restrict__ btot,
                                                          int* __restrict__ rowptr,
                                                          int* __restrict__ pbt,
                                                          float* __restrict__ dinv,
                                                          const int* __restrict__ batch,
                                                          int* __restrict__ gcnt, int N) {
    if ((int)blockIdx.x == NB) {
        int g = threadIdx.x;
        if (g >= NGRAPH) return;
        auto lb = [&](int v) {
            int lo = 0, hi = N;
            while (lo < hi) {
                int mid = (lo + hi) >> 1;
                if (batch[mid] < v) lo = mid + 1; else hi = mid;
            }
            return lo;
        };
        gcnt[g] = lb(g + 1) - lb(g);
        return;
    }
    __shared__ int c256[256];
    __shared__ int s[256];
    int t = threadIdx.x;
    c256[t] = 0;
    __syncthreads();
    int lo = bbase[blockIdx.x], n = btot[blockIdx.x];
    for (int e = lo + t; e < lo + n; e += 256) atomicAdd(&c256[dst_b[e] & 255], 1);
    __syncthreads();
    int cnt = c256[t];
    int pcnt = (cnt + 7) & ~7;   // pad to multiple of 8
    s[t] = pcnt;
    __syncthreads();
    for (int d = 1; d < 256; d <<= 1) {
        int x = (t >= d) ? s[t - d] : 0;
        __syncthreads();
        s[t] += x;
        __syncthreads();
    }
    int node = blockIdx.x * 256 + t;
    if (node < N) {
        rowptr[node] = s[t] - pcnt;
        dinv[node] = 1.0f / sqrtf((float)(cnt + 1));  // +1 self-loop (real degree)
    }
    if (t == 255) pbt[blockIdx.x] = s[255];
}

// ---- rowptr fixup: add padded bucket base; set rowptr[N] = grand total ----
__global__ void rowptr_fix_kernel(int* __restrict__ rowptr, const int* __restrict__ pbbase,
                                  int N) {
    int i = blockIdx.x * 256 + threadIdx.x;
    if (i < N) rowptr[i] += pbbase[i >> 8];
    if (i == 0) rowptr[N] = pbbase[NB];
}

// ---------------- bucket_fill: padded CSR (col only), LDS ranks; pad -> N ----------------
__global__ __launch_bounds__(256) void bucket_fill_kernel(const int* __restrict__ src_b,
                                                          const int* __restrict__ dst_b,
                                                          const int* __restrict__ bbase,
                                                          const int* __restrict__ btot,
                                                          const int* __restrict__ rowptr,
                                                          int* __restrict__ col, int N) {
    __shared__ int f256[256];
    __shared__ int rp[256];
    int t = threadIdx.x;
    f256[t] = 0;
    int node = blockIdx.x * 256 + t;
    rp[t] = (node < N) ? rowptr[node] : 0;
    __syncthreads();
    int lo = bbase[blockIdx.x], n = btot[blockIdx.x];
    for (int e = lo + t; e < lo + n; e += 256) {
        int d = dst_b[e], sv = src_b[e];
        int li = d & 255;
        int slot = atomicAdd(&f256[li], 1);   // LDS atomic
        col[rp[li] + slot] = sv;
    }
    __syncthreads();
    if (node < N) {   // fill padding with zero-row index N
        int c = f256[t];
        int pc = (c + 7) & ~7;
        int base = rp[t];
        for (int p = c; p < pc; ++p) col[base + p] = N;
    }
}

// ---------------- scale m rows by dinv + zero the pad row N ----------------
__global__ __launch_bounds__(256) void scale_m_kernel(__half* __restrict__ m,
                                                      __half* __restrict__ other,
                                                      const float* __restrict__ dinv, int N) {
    if (blockIdx.x == 0 && threadIdx.x < 64) {
        m[(size_t)N * 64 + threadIdx.x] = __float2half(0.0f);
        other[(size_t)N * 64 + threadIdx.x] = __float2half(0.0f);
    }
    int tot = N * 32;   // half2 elements
    __half2* m2 = (__half2*)m;
    for (int idx = blockIdx.x * 256 + threadIdx.x; idx < tot; idx += gridDim.x * 256) {
        float d = dinv[idx >> 5];
        float2 f = __half22float2(m2[idx]);
        f.x *= d;
        f.y *= d;
        m2[idx] = __float22half2_rn(f);
    }
}

// Pair gather over contiguous padded ranges [r0,mid)->A, [mid,r1)->B.
// All bounds multiples of 8 -> no tails/predication; col indices scalar (s_load).
__device__ __forceinline__ void pair_gather(const __half* __restrict__ h,
                                            const int* __restrict__ col,
                                            int r0, int mid, int r1, int lane,
                                            float& aA, float& aB) {
    int n = r1 - r0;
    int e = 0;
    for (; e + 16 <= n; e += 16) {
        int base = r0 + e;
        int c[16];
        float v[16];
#pragma unroll
        for (int u = 0; u < 16; ++u) c[u] = col[base + u];
#pragma unroll
        for (int u = 0; u < 16; ++u) v[u] = __half2float(h[(size_t)c[u] * 64 + lane]);
        float s0 = ((v[0] + v[1]) + (v[2] + v[3])) + ((v[4] + v[5]) + (v[6] + v[7]));
        float s1 = ((v[8] + v[9]) + (v[10] + v[11])) + ((v[12] + v[13]) + (v[14] + v[15]));
        bool b0 = (base < mid);
        bool b1 = (base + 8 < mid);
        aA += b0 ? s0 : 0.0f;
        aB += b0 ? 0.0f : s0;
        aA += b1 ? s1 : 0.0f;
        aB += b1 ? 0.0f : s1;
    }
    if (e + 8 <= n) {   // remainder is exactly 0 or 8
        int base = r0 + e;
        int c[8];
        float v[8];
#pragma unroll
        for (int u = 0; u < 8; ++u) c[u] = col[base + u];
#pragma unroll
        for (int u = 0; u < 8; ++u) v[u] = __half2float(h[(size_t)c[u] * 64 + lane]);
        float s0 = ((v[0] + v[1]) + (v[2] + v[3])) + ((v[4] + v[5]) + (v[6] + v[7]));
        bool b0 = (base < mid);
        aA += b0 ? s0 : 0.0f;
        aB += b0 ? 0.0f : s0;
    }
}

// ---------------- layer-0 aggregation (2 nodes/wave, m pre-scaled) ----------------
__global__ __launch_bounds__(256) void agg0_kernel(const __half* __restrict__ m,
                                                   const int* __restrict__ rowptr,
                                                   const int* __restrict__ col,
                                                   const float* __restrict__ dinv,
                                                   const float* __restrict__ bias,
                                                   __half* __restrict__ hout, int N) {
    int wid = __builtin_amdgcn_readfirstlane((blockIdx.x * 256 + threadIdx.x) >> 6);
    int lane = threadIdx.x & 63;
    int nodeA = wid * 2;
    int nodeB = nodeA + 1;   // N even
    if (nodeA >= N) return;
    int r0 = rowptr[nodeA];
    int mid = rowptr[nodeB];
    int r1 = rowptr[nodeB + 1];
    float diA = dinv[nodeA], diB = dinv[nodeB];
    float aA = __half2float(m[(size_t)nodeA * 64 + lane]);   // self (pre-scaled)
    float aB = __half2float(m[(size_t)nodeB * 64 + lane]);
    pair_gather(m, col, r0, mid, r1, lane, aA, aB);
    float bv = bias[lane];
    float hA = fmaxf(diA * aA + bv, 0.0f);
    float hB = fmaxf(diB * aB + bv, 0.0f);
    hout[(size_t)nodeA * 64 + lane] = __float2half(diA * hA);   // pre-scaled out
    hout[(size_t)nodeB * 64 + lane] = __float2half(diB * hB);
}

// ---------------- fused layer, 8 nodes/block: h' = relu((A h) W + b) ----------------
// Gather per wave (2 nodes) -> g rows staged to LDS -> per-wave MFMA GEMM
// (wave = one 16-col tile; bf16-split 3-MFMA; B-frags pre-packed in global,
// L2-resident). Replaces the 256-VALU-op readlane GEMM (r17 profile: 70% of
// wave VALU) with ~80 ops + 6 MFMA. A rows 8-15 of the 16x16 tile are unused
// garbage; they only affect discarded output rows (no cross-row mixing).
__global__ __launch_bounds__(256) void fused_kernel(const __half* __restrict__ h,
                                                    const int* __restrict__ rowptr,
                                                    const int* __restrict__ col,
                                                    const float* __restrict__ dinv,
                                                    const unsigned short* __restrict__ wfh,
                                                    const unsigned short* __restrict__ wfl,
                                                    const float* __restrict__ bias,
                                                    __half* __restrict__ hout, int N,
                                                    int scaleOut) {
    __shared__ float gLds[16][68];   // 8 valid rows; +68 pad keeps b128 reads aligned/conflict-lite

    int wave = __builtin_amdgcn_readfirstlane((int)(threadIdx.x >> 6));
    int lane = threadIdx.x & 63;
    int node0 = blockIdx.x * 8;      // N % 8 == 0, grid = N/8 -> all valid
    int nodeA = node0 + wave * 2;
    int nodeB = nodeA + 1;

    int r0 = rowptr[nodeA];
    int mid = rowptr[nodeB];
    int r1 = rowptr[nodeB + 1];
    float diA = dinv[nodeA], diB = dinv[nodeB];
    float aA = __half2float(h[(size_t)nodeA * 64 + lane]);   // self (pre-scaled)
    float aB = __half2float(h[(size_t)nodeB * 64 + lane]);
    pair_gather(h, col, r0, mid, r1, lane, aA, aB);
    gLds[wave * 2][lane] = diA * aA;
    gLds[wave * 2 + 1][lane] = diB * aB;

    __syncthreads();

    // GEMM: this wave computes output cols [wave*16, wave*16+16) for rows 0..7
    int arow = lane & 15;
    int kg = lane >> 4;
    f32x4 acc = {0.0f, 0.0f, 0.0f, 0.0f};
#pragma unroll
    for (int s = 0; s < 2; ++s) {
        const float* ap = &gLds[arow][s * 32 + kg * 8];
        float xv[8];
#pragma unroll
        for (int i = 0; i < 8; ++i) xv[i] = ap[i];
        // hi = truncate-to-bf16 (v_perm pack), lo = exact remainder rounded (cvt_pk)
        union { bf16x8 v; unsigned u[4]; } ahi, alo;
#pragma unroll
        for (int p = 0; p < 4; ++p) {
            unsigned u0 = __float_as_uint(xv[2 * p]);
            unsigned u1 = __float_as_uint(xv[2 * p + 1]);
            ahi.u[p] = __builtin_amdgcn_perm(u1, u0, 0x07060302);   // [u1_hi16 : u0_hi16]
            float l0 = xv[2 * p] - __uint_as_float(u0 & 0xFFFF0000u);
            float l1 = xv[2 * p + 1] - __uint_as_float(u1 & 0xFFFF0000u);
            unsigned r;
            asm("v_cvt_pk_bf16_f32 %0, %1, %2" : "=v"(r) : "v"(l0), "v"(l1));
            alo.u[p] = r;
        }
        const bf16x8 b_hi = *(const bf16x8*)(wfh + ((size_t)(s * 4 + wave) * 64 + lane) * 8);
        const bf16x8 b_lo = *(const bf16x8*)(wfl + ((size_t)(s * 4 + wave) * 64 + lane) * 8);
        acc = __builtin_amdgcn_mfma_f32_16x16x32_bf16(ahi.v, b_hi, acc, 0, 0, 0);
        acc = __builtin_amdgcn_mfma_f32_16x16x32_bf16(ahi.v, b_lo, acc, 0, 0, 0);
        acc = __builtin_amdgcn_mfma_f32_16x16x32_bf16(alo.v, b_hi, acc, 0, 0, 0);
    }

    // epilogue: D row=(lane>>4)*4+r (keep rows<8), col=wave*16+(lane&15)
    int dcol = wave * 16 + (lane & 15);
    int rbase = (lane >> 4) * 4;
    if (rbase < 8) {
        float bv = bias[dcol];
#pragma unroll
        for (int r = 0; r < 4; ++r) {
            int nd = node0 + rbase + r;
            float v = fmaxf(acc[r] + bv, 0.0f);
            if (scaleOut) v *= dinv[nd];   // pre-scale for next layer's gather
            hout[(size_t)nd * 64 + dcol] = __float2half(v);
        }
    }
}

// ---------------- pooling: segment sum over sorted batch ids ----------------
__global__ __launch_bounds__(256) void pool_kernel(const __half* __restrict__ h,
                                                   const int* __restrict__ batch,
                                                   float* __restrict__ gpool, int N) {
    const int NPW = 32;  // nodes per wave
    int wid = (blockIdx.x * 256 + threadIdx.x) >> 6;
    int lane = threadIdx.x & 63;
    int i0 = wid * NPW;
    if (i0 >= N) return;
    int i1 = min(i0 + NPW, N);
    int curg = batch[i0];
    float acc = 0.0f;
    for (int i = i0; i < i1; ++i) {
        int g = batch[i];
        if (g != curg) {
            atomicAdd(&gpool[curg * 64 + lane], acc);
            acc = 0.0f;
            curg = g;
        }
        acc += __half2float(h[(size_t)i * 64 + lane]);
    }
    atomicAdd(&gpool[curg * 64 + lane], acc);
}

// ---------------- final: out = (gpool/count) @ Wlin + blin ----------------
__global__ void final_kernel(const float* __restrict__ gpool, const int* __restrict__ gcnt,
                             const float* __restrict__ Wlin, const float* __restrict__ blin,
                             float* __restrict__ out) {
    int t = threadIdx.x;
    if (t >= NGRAPH * COUT) return;
    int g = t / COUT, o = t - g * COUT;
    float c = (float)gcnt[g];
    if (c < 1.0f) c = 1.0f;
    float s = 0.0f;
    for (int k = 0; k < 64; ++k) s += gpool[g * 64 + k] * Wlin[k * COUT + o];
    out[t] = s / c + blin[o];
}

extern "C" void kernel_launch(void* const* d_in, const int* in_sizes, int n_in,
                              void* d_out, int out_size, void* d_ws, size_t ws_size,
                              hipStream_t stream) {
    const float* x    = (const float*)d_in[0];
    const int*   ei   = (const int*)d_in[1];
    const int*   batch= (const int*)d_in[2];
    const float* W0   = (const float*)d_in[3];
    const float* b0   = (const float*)d_in[4];
    const float* Ws   = (const float*)d_in[5];
    const float* bs   = (const float*)d_in[6];
    const float* Wlin = (const float*)d_in[7];
    const float* blin = (const float*)d_in[8];
    float* out = (float*)d_out;

    const int N = NNODES, E = NEDGES;
    const int* srcp = ei;          // edge_index[0]
    const int* dstp = ei + E;      // edge_index[1]

    char* w = (char*)d_ws;
    float* gpool  = (float*)w; w += (size_t)NGRAPH * 64 * 4;
    size_t zero_bytes = (size_t)(w - (char*)d_ws);   // only gpool needs zeroing
    int*   gcnt   = (int*)w;   w += (size_t)NGRAPH * 4;
    float* dinv   = (float*)w; w += (size_t)N * 4;
    int*   rowptr = (int*)w;   w += (size_t)(N + 1) * 4;
    int*   hist   = (int*)w;   w += (size_t)NB * NC * 4;
    int*   btot   = (int*)w;   w += (size_t)NB * 4;
    int*   bbase  = (int*)w;   w += (size_t)(NB + 1) * 4;
    int*   pbt    = (int*)w;   w += (size_t)NB * 4;
    int*   pbbase = (int*)w;   w += (size_t)(NB + 1) * 4;
    int*   src_b  = (int*)w;   w += (size_t)E * 4;
    int*   dst_b  = (int*)w;   w += (size_t)E * 4;
    int*   col    = (int*)w;   w += ((size_t)E + 8 * N) * 4;   // padded CSR
    unsigned short* wfh = (unsigned short*)w; w += (size_t)NSTACK * 4096 * 2;
    unsigned short* wfl = (unsigned short*)w; w += (size_t)NSTACK * 4096 * 2;
    __half* bufA  = (__half*)w; w += (size_t)(N + 1) * 64 * 2;  // +zero row N
    __half* bufB  = (__half*)w; w += (size_t)(N + 1) * 64 * 2;

    hipMemsetAsync(d_ws, 0, zero_bytes, stream);

    int nblocks = (N + 255) / 256;       // 391
    int gemmblocks = (N + 63) / 64;      // 1563: 16 rows/wave (MFMA), 4 waves/block

    pack_wfrags_kernel<<<NSTACK * 8, 256, 0, stream>>>(Ws, wfh, wfl);
    // P1 histogram + layer-0 MFMA GEMM co-scheduled (independent)
    hist_gemm_kernel<<<NC + gemmblocks, 256, 0, stream>>>(
        dstp, hist, E, x, W0, bufB, N, NC);
    scan_chunks_kernel<<<NB, 256, 0, stream>>>(hist, btot);
    scan_buckets_kernel<<<1, 512, 0, stream>>>(btot, bbase);
    scatter_kernel<<<NC, 256, 0, stream>>>(srcp, dstp, hist, bbase, src_b, dst_b, E);
    bucket_prep_kernel<<<NB + 1, 256, 0, stream>>>(dst_b, bbase, btot, rowptr, pbt, dinv,
                                                   batch, gcnt, N);
    scan_buckets_kernel<<<1, 512, 0, stream>>>(pbt, pbbase);
    rowptr_fix_kernel<<<nblocks, 256, 0, stream>>>(rowptr, pbbase, N);
    bucket_fill_kernel<<<NB, 256, 0, stream>>>(src_b, dst_b, bbase, btot, rowptr, col, N);
    scale_m_kernel<<<2048, 256, 0, stream>>>(bufB, bufA, dinv, N);

    int pairblocks = (N / 2 + 3) / 4;     // 2 nodes/wave, 4 waves/block (agg0)
    int fusedblocks = N / 8;              // 8 nodes/block (fused, MFMA GEMM)

    agg0_kernel<<<pairblocks, 256, 0, stream>>>(bufB, rowptr, col, dinv, b0, bufA, N);

    // layers 1..9 fused: h' = relu((A h) W + b); rows pre-scaled except the last
    __half* hin = bufA;
    __half* hout = bufB;
    for (int l = 0; l < NSTACK; ++l) {
        int scaleOut = (l < NSTACK - 1) ? 1 : 0;
        fused_kernel<<<fusedblocks, 256, 0, stream>>>(hin, rowptr, col, dinv,
                                                      wfh + (size_t)l * 4096,
                                                      wfl + (size_t)l * 4096,
                                                      bs + (size_t)l * 64, hout, N,
                                                      scaleOut);
        __half* t = hin; hin = hout; hout = t;
    }
    // final h is in `hin` after the swap

    int pwaves = (N + 31) / 32;
    int pblocks = (pwaves + 3) / 4;
    pool_kernel<<<pblocks, 256, 0, stream>>>(hin, batch, gpool, N);
    final_kernel<<<1, 896, 0, stream>>>(gpool, gcnt, Wlin, blin, out);
}

// Round 19
// 622.781 us; speedup vs baseline: 1.1143x; 1.0060x over previous
//
#include <hip/hip_runtime.h>
#include <hip/hip_fp16.h>

#define NNODES 100000
#define NEDGES 1600000
#define NGRAPH 128
#define CIN 128
#define CH 64
#define COUT 7
#define NSTACK 9

#define NB 391      // buckets of 256 nodes: ceil(100000/256)
#define CHUNK 2048  // edges per histogram/scatter block
#define NC 782      // ceil(1600000/2048)

typedef __attribute__((ext_vector_type(8))) short bf16x8;
typedef __attribute__((ext_vector_type(4))) float f32x4;

__device__ __forceinline__ unsigned short f2bf(float f) {
    unsigned u = __float_as_uint(f);
    return (unsigned short)((u + 0x7FFFu + ((u >> 16) & 1u)) >> 16);
}

// ---------------- merged: P1 bucket histogram (LDS only) + layer-0 MFMA GEMM ----------
// bf16-split MFMA (x_hi@W_hi + x_hi@W_lo + x_lo@W_hi): ~16-bit mantissa, more
// accurate than the fp16 store that follows. Fragment layouts validated r17.
__global__ __launch_bounds__(256) void hist_gemm_kernel(const int* __restrict__ dst,
                                                        int* __restrict__ hist, int E,
                                                        const float* __restrict__ h,
                                                        const float* __restrict__ W,
                                                        __half* __restrict__ m, int N,
                                                        int histBlocks) {
    __shared__ alignas(16) char smem[32768 + 2048];
    if (blockIdx.x < (unsigned)histBlocks) {
        int* lh = (int*)smem;
        for (int i = threadIdx.x; i < NB; i += 256) lh[i] = 0;
        __syncthreads();
        int e0 = blockIdx.x * CHUNK;
        int e1 = min(e0 + CHUNK, E);
        for (int e = e0 + threadIdx.x; e < e1; e += 256)
            atomicAdd(&lh[dst[e] >> 8], 1);   // LDS atomic
        __syncthreads();
        for (int i = threadIdx.x; i < NB; i += 256) hist[i * NC + (int)blockIdx.x] = lh[i];
        return;
    }
    // ---- GEMM part: 64 rows/block, 16 rows/wave, MFMA 16x16x32 bf16 ----
    int gb = blockIdx.x - histBlocks;
    unsigned short* wf_hi = (unsigned short*)smem;        // [16 combos][64 lanes][8]
    unsigned short* wf_lo = wf_hi + 16 * 64 * 8;          // 16KB each
    int t = threadIdx.x;

    {
        int c = t >> 4;            // 0..15
        int kstep = c >> 2, ncol = c & 3;
        int l0 = (t & 15) * 4;     // 4 lanes per thread
        for (int dl = 0; dl < 4; ++dl) {
            int l = l0 + dl;
            int kbase = kstep * 32 + (l >> 4) * 8;
            int n = ncol * 16 + (l & 15);
            for (int i = 0; i < 8; ++i) {
                float wv = W[(size_t)(kbase + i) * 64 + n];
                unsigned short hb = f2bf(wv);
                float hf = __uint_as_float(((unsigned)hb) << 16);
                wf_hi[((size_t)c * 64 + l) * 8 + i] = hb;
                wf_lo[((size_t)c * 64 + l) * 8 + i] = f2bf(wv - hf);
            }
        }
    }
    __syncthreads();

    int wave = t >> 6, lane = t & 63;
    long row0 = (long)gb * 64 + wave * 16;
    if (row0 >= N) return;

    long arow = row0 + (lane & 15);
    const float4* xr = (const float4*)(h + (size_t)arow * 128);
    int kg = lane >> 4;   // 0..3

    f32x4 zero = {0.0f, 0.0f, 0.0f, 0.0f};
    f32x4 acc[4];
    acc[0] = zero; acc[1] = zero; acc[2] = zero; acc[3] = zero;

#pragma unroll
    for (int s = 0; s < 4; ++s) {
        float4 p = xr[s * 8 + kg * 2];
        float4 q = xr[s * 8 + kg * 2 + 1];
        float xv[8] = {p.x, p.y, p.z, p.w, q.x, q.y, q.z, q.w};
        bf16x8 a_hi, a_lo;
#pragma unroll
        for (int i = 0; i < 8; ++i) {
            unsigned short hb = f2bf(xv[i]);
            a_hi[i] = (short)hb;
            a_lo[i] = (short)f2bf(xv[i] - __uint_as_float(((unsigned)hb) << 16));
        }
#pragma unroll
        for (int nc = 0; nc < 4; ++nc) {
            int c = s * 4 + nc;
            bf16x8 b_hi = *(const bf16x8*)(wf_hi + ((size_t)c * 64 + lane) * 8);
            bf16x8 b_lo = *(const bf16x8*)(wf_lo + ((size_t)c * 64 + lane) * 8);
            acc[nc] = __builtin_amdgcn_mfma_f32_16x16x32_bf16(a_hi, b_hi, acc[nc], 0, 0, 0);
            acc[nc] = __builtin_amdgcn_mfma_f32_16x16x32_bf16(a_hi, b_lo, acc[nc], 0, 0, 0);
            acc[nc] = __builtin_amdgcn_mfma_f32_16x16x32_bf16(a_lo, b_hi, acc[nc], 0, 0, 0);
        }
    }

    int drow = (lane >> 4) * 4;
    int dcol = lane & 15;
#pragma unroll
    for (int nc = 0; nc < 4; ++nc)
#pragma unroll
        for (int r = 0; r < 4; ++r)
            m[(size_t)(row0 + drow + r) * 64 + nc * 16 + dcol] = __float2half(acc[nc][r]);
}

// ---- pack all 9 stacked-layer W matrices into MFMA B-fragment order (bf16 hi/lo) ----
__global__ void pack_wfrags_kernel(const float* __restrict__ Ws,
                                   unsigned short* __restrict__ wfh,
                                   unsigned short* __restrict__ wfl) {
    int b = blockIdx.x;        // 0..71 = l*8 + c
    int l = b >> 3, c = b & 7;
    int s = c >> 2, nc = c & 3;
    for (int v = threadIdx.x; v < 512; v += 256) {
        int L = v >> 3, i = v & 7;
        int k = s * 32 + (L >> 4) * 8 + i;
        int n = nc * 16 + (L & 15);
        float w = Ws[(size_t)l * 4096 + k * 64 + n];
        unsigned short hb = f2bf(w);
        float hf = __uint_as_float(((unsigned)hb) << 16);
        size_t idx = ((size_t)b * 64 + L) * 8 + i;
        wfh[idx] = hb;
        wfl[idx] = f2bf(w - hf);
    }
}

// ---------------- P2a: exclusive scan of each bucket row over NC chunks ----------------
__global__ __launch_bounds__(256) void scan_chunks_kernel(int* __restrict__ hist,
                                                          int* __restrict__ btot) {
    int b = blockIdx.x;
    int t = threadIdx.x;
    int* row = hist + b * NC;
    int v[4];
    int base = 4 * t;
#pragma unroll
    for (int u = 0; u < 4; ++u) v[u] = (base + u < NC) ? row[base + u] : 0;
    int tsum = v[0] + v[1] + v[2] + v[3];
    __shared__ int s[256];
    s[t] = tsum;
    __syncthreads();
    for (int d = 1; d < 256; d <<= 1) {
        int x = (t >= d) ? s[t - d] : 0;
        __syncthreads();
        s[t] += x;
        __syncthreads();
    }
    int run = s[t] - tsum;
    if (t == 255) btot[b] = s[255];
#pragma unroll
    for (int u = 0; u < 4; ++u) {
        if (base + u < NC) row[base + u] = run;
        run += v[u];
    }
}

// ---- exclusive scan of NB totals -> bases; also writes grand total at out[NB] ----
__global__ void scan_buckets_kernel(const int* __restrict__ tot, int* __restrict__ out) {
    __shared__ int s[512];
    int t = threadIdx.x;
    int v = (t < NB) ? tot[t] : 0;
    s[t] = v;
    __syncthreads();
    for (int d = 1; d < 512; d <<= 1) {
        int x = (t >= d) ? s[t - d] : 0;
        __syncthreads();
        s[t] += x;
        __syncthreads();
    }
    if (t < NB) out[t] = s[t] - v;
    if (t == NB - 1) out[NB] = s[t];
}

// ---------------- P3: scatter edges into dst buckets, XCD-class-routed ----------------
// Block (chunk=blockIdx>>3, cls=blockIdx&7) handles only edges with
// (dst>>8)&7==cls: bucket b is written EXCLUSIVELY by class b&7 (~one XCD via
// round-robin blockIdx->XCD) -> full dirty lines, no cross-XCD partial-line
// writeback (r18 profile: 77.7MB WRITE for 12.8MB payload). Packed int2 store
// halves scattered stores. Cost: 8x dst re-read, LLC-resident (~r5 fill trade).
__global__ __launch_bounds__(256) void scatter_kernel(const int* __restrict__ src,
                                                      const int* __restrict__ dst,
                                                      const int* __restrict__ hist,
                                                      const int* __restrict__ bbase,
                                                      int2* __restrict__ edge_b, int E) {
    __shared__ int offs[NB];
    int ck = blockIdx.x >> 3;
    int cls = blockIdx.x & 7;
    for (int b = threadIdx.x; b < NB; b += 256)
        offs[b] = hist[b * NC + ck] + bbase[b];
    __syncthreads();
    int e0 = ck * CHUNK;
    int e1 = min(e0 + CHUNK, E);
    for (int e = e0 + threadIdx.x; e < e1; e += 256) {
        int d = dst[e];
        if (((d >> 8) & 7) == cls) {
            int s = src[e];
            int pos = atomicAdd(&offs[d >> 8], 1);   // LDS atomic
            edge_b[pos] = make_int2(s, d);
        }
    }
}

// ---- bucket_prep: degree count + PADDED in-bucket rowptr offsets + dinv (+gcnt) ----
__global__ __launch_bounds__(256) void bucket_prep_kernel(const int2* __restrict__ edge_b,
                                                          const int* __restrict__ bbase,
                                                          const int* __restrict__ btot,
                                                          int* __restrict__ rowptr,
                                                          int* __restrict__ pbt,
                                                          float* __restrict__ dinv,
                                                          const int* __restrict__ batch,
                                                          int* __restrict__ gcnt, int N) {
    if ((int)blockIdx.x == NB) {
        int g = threadIdx.x;
        if (g >= NGRAPH) return;
        auto lb = [&](int v) {
            int lo = 0, hi = N;
            while (lo < hi) {
                int mid = (lo + hi) >> 1;
                if (batch[mid] < v) lo = mid + 1; else hi = mid;
            }
            return lo;
        };
        gcnt[g] = lb(g + 1) - lb(g);
        return;
    }
    __shared__ int c256[256];
    __shared__ int s[256];
    int t = threadIdx.x;
    c256[t] = 0;
    __syncthreads();
    int lo = bbase[blockIdx.x], n = btot[blockIdx.x];
    for (int e = lo + t; e < lo + n; e += 256) atomicAdd(&c256[edge_b[e].y & 255], 1);
    __syncthreads();
    int cnt = c256[t];
    int pcnt = (cnt + 7) & ~7;   // pad to multiple of 8
    s[t] = pcnt;
    __syncthreads();
    for (int d = 1; d < 256; d <<= 1) {
        int x = (t >= d) ? s[t - d] : 0;
        __syncthreads();
        s[t] += x;
        __syncthreads();
    }
    int node = blockIdx.x * 256 + t;
    if (node < N) {
        rowptr[node] = s[t] - pcnt;
        dinv[node] = 1.0f / sqrtf((float)(cnt + 1));  // +1 self-loop (real degree)
    }
    if (t == 255) pbt[blockIdx.x] = s[255];
}

// ---- rowptr fixup: add padded bucket base; set rowptr[N] = grand total ----
__global__ void rowptr_fix_kernel(int* __restrict__ rowptr, const int* __restrict__ pbbase,
                                  int N) {
    int i = blockIdx.x * 256 + threadIdx.x;
    if (i < N) rowptr[i] += pbbase[i >> 8];
    if (i == 0) rowptr[N] = pbbase[NB];
}

// ---------------- bucket_fill: padded CSR (col only), LDS ranks; pad -> N ----------------
__global__ __launch_bounds__(256) void bucket_fill_kernel(const int2* __restrict__ edge_b,
                                                          const int* __restrict__ bbase,
                                                          const int* __restrict__ btot,
                                                          const int* __restrict__ rowptr,
                                                          int* __restrict__ col, int N) {
    __shared__ int f256[256];
    __shared__ int rp[256];
    int t = threadIdx.x;
    f256[t] = 0;
    int node = blockIdx.x * 256 + t;
    rp[t] = (node < N) ? rowptr[node] : 0;
    __syncthreads();
    int lo = bbase[blockIdx.x], n = btot[blockIdx.x];
    for (int e = lo + t; e < lo + n; e += 256) {
        int2 ed = edge_b[e];
        int li = ed.y & 255;
        int slot = atomicAdd(&f256[li], 1);   // LDS atomic
        col[rp[li] + slot] = ed.x;
    }
    __syncthreads();
    if (node < N) {   // fill padding with zero-row index N
        int c = f256[t];
        int pc = (c + 7) & ~7;
        int base = rp[t];
        for (int p = c; p < pc; ++p) col[base + p] = N;
    }
}

// ---------------- scale m rows by dinv + zero the pad row N ----------------
__global__ __launch_bounds__(256) void scale_m_kernel(__half* __restrict__ m,
                                                      __half* __restrict__ other,
                                                      const float* __restrict__ dinv, int N) {
    if (blockIdx.x == 0 && threadIdx.x < 64) {
        m[(size_t)N * 64 + threadIdx.x] = __float2half(0.0f);
        other[(size_t)N * 64 + threadIdx.x] = __float2half(0.0f);
    }
    int tot = N * 32;   // half2 elements
    __half2* m2 = (__half2*)m;
    for (int idx = blockIdx.x * 256 + threadIdx.x; idx < tot; idx += gridDim.x * 256) {
        float d = dinv[idx >> 5];
        float2 f = __half22float2(m2[idx]);
        f.x *= d;
        f.y *= d;
        m2[idx] = __float22half2_rn(f);
    }
}

// Pair gather over contiguous padded ranges [r0,mid)->A, [mid,r1)->B.
// All bounds multiples of 8 -> no tails/predication; col indices scalar (s_load).
__device__ __forceinline__ void pair_gather(const __half* __restrict__ h,
                                            const int* __restrict__ col,
                                            int r0, int mid, int r1, int lane,
                                            float& aA, float& aB) {
    int n = r1 - r0;
    int e = 0;
    for (; e + 16 <= n; e += 16) {
        int base = r0 + e;
        int c[16];
        float v[16];
#pragma unroll
        for (int u = 0; u < 16; ++u) c[u] = col[base + u];
#pragma unroll
        for (int u = 0; u < 16; ++u) v[u] = __half2float(h[(size_t)c[u] * 64 + lane]);
        float s0 = ((v[0] + v[1]) + (v[2] + v[3])) + ((v[4] + v[5]) + (v[6] + v[7]));
        float s1 = ((v[8] + v[9]) + (v[10] + v[11])) + ((v[12] + v[13]) + (v[14] + v[15]));
        bool b0 = (base < mid);
        bool b1 = (base + 8 < mid);
        aA += b0 ? s0 : 0.0f;
        aB += b0 ? 0.0f : s0;
        aA += b1 ? s1 : 0.0f;
        aB += b1 ? 0.0f : s1;
    }
    if (e + 8 <= n) {   // remainder is exactly 0 or 8
        int base = r0 + e;
        int c[8];
        float v[8];
#pragma unroll
        for (int u = 0; u < 8; ++u) c[u] = col[base + u];
#pragma unroll
        for (int u = 0; u < 8; ++u) v[u] = __half2float(h[(size_t)c[u] * 64 + lane]);
        float s0 = ((v[0] + v[1]) + (v[2] + v[3])) + ((v[4] + v[5]) + (v[6] + v[7]));
        bool b0 = (base < mid);
        aA += b0 ? s0 : 0.0f;
        aB += b0 ? 0.0f : s0;
    }
}

// ---------------- layer-0 aggregation (2 nodes/wave, m pre-scaled) ----------------
__global__ __launch_bounds__(256) void agg0_kernel(const __half* __restrict__ m,
                                                   const int* __restrict__ rowptr,
                                                   const int* __restrict__ col,
                                                   const float* __restrict__ dinv,
                                                   const float* __restrict__ bias,
                                                   __half* __restrict__ hout, int N) {
    int wid = __builtin_amdgcn_readfirstlane((blockIdx.x * 256 + threadIdx.x) >> 6);
    int lane = threadIdx.x & 63;
    int nodeA = wid * 2;
    int nodeB = nodeA + 1;   // N even
    if (nodeA >= N) return;
    int r0 = rowptr[nodeA];
    int mid = rowptr[nodeB];
    int r1 = rowptr[nodeB + 1];
    float diA = dinv[nodeA], diB = dinv[nodeB];
    float aA = __half2float(m[(size_t)nodeA * 64 + lane]);   // self (pre-scaled)
    float aB = __half2float(m[(size_t)nodeB * 64 + lane]);
    pair_gather(m, col, r0, mid, r1, lane, aA, aB);
    float bv = bias[lane];
    float hA = fmaxf(diA * aA + bv, 0.0f);
    float hB = fmaxf(diB * aB + bv, 0.0f);
    hout[(size_t)nodeA * 64 + lane] = __float2half(diA * hA);   // pre-scaled out
    hout[(size_t)nodeB * 64 + lane] = __float2half(diB * hB);
}

// ---------------- fused layer, 8 nodes/block: h' = relu((A h) W + b) ----------------
// Gather per wave (2 nodes) -> g rows staged to LDS -> per-wave MFMA GEMM
// (bf16-split 3-MFMA; B-frags pre-packed in global, L2-resident).
__global__ __launch_bounds__(256) void fused_kernel(const __half* __restrict__ h,
                                                    const int* __restrict__ rowptr,
                                                    const int* __restrict__ col,
                                                    const float* __restrict__ dinv,
                                                    const unsigned short* __restrict__ wfh,
                                                    const unsigned short* __restrict__ wfl,
                                                    const float* __restrict__ bias,
                                                    __half* __restrict__ hout, int N,
                                                    int scaleOut) {
    __shared__ float gLds[16][68];

    int wave = __builtin_amdgcn_readfirstlane((int)(threadIdx.x >> 6));
    int lane = threadIdx.x & 63;
    int node0 = blockIdx.x * 8;      // N % 8 == 0, grid = N/8 -> all valid
    int nodeA = node0 + wave * 2;
    int nodeB = nodeA + 1;

    int r0 = rowptr[nodeA];
    int mid = rowptr[nodeB];
    int r1 = rowptr[nodeB + 1];
    float diA = dinv[nodeA], diB = dinv[nodeB];
    float aA = __half2float(h[(size_t)nodeA * 64 + lane]);   // self (pre-scaled)
    float aB = __half2float(h[(size_t)nodeB * 64 + lane]);
    pair_gather(h, col, r0, mid, r1, lane, aA, aB);
    gLds[wave * 2][lane] = diA * aA;
    gLds[wave * 2 + 1][lane] = diB * aB;

    __syncthreads();

    // GEMM: this wave computes output cols [wave*16, wave*16+16) for rows 0..7
    int arow = lane & 15;
    int kg = lane >> 4;
    f32x4 acc = {0.0f, 0.0f, 0.0f, 0.0f};
#pragma unroll
    for (int s = 0; s < 2; ++s) {
        const float* ap = &gLds[arow][s * 32 + kg * 8];
        float xv[8];
#pragma unroll
        for (int i = 0; i < 8; ++i) xv[i] = ap[i];
        union { bf16x8 v; unsigned u[4]; } ahi, alo;
#pragma unroll
        for (int p = 0; p < 4; ++p) {
            unsigned u0 = __float_as_uint(xv[2 * p]);
            unsigned u1 = __float_as_uint(xv[2 * p + 1]);
            ahi.u[p] = __builtin_amdgcn_perm(u1, u0, 0x07060302);   // [u1_hi16 : u0_hi16]
            float l0 = xv[2 * p] - __uint_as_float(u0 & 0xFFFF0000u);
            float l1 = xv[2 * p + 1] - __uint_as_float(u1 & 0xFFFF0000u);
            unsigned r;
            asm("v_cvt_pk_bf16_f32 %0, %1, %2" : "=v"(r) : "v"(l0), "v"(l1));
            alo.u[p] = r;
        }
        const bf16x8 b_hi = *(const bf16x8*)(wfh + ((size_t)(s * 4 + wave) * 64 + lane) * 8);
        const bf16x8 b_lo = *(const bf16x8*)(wfl + ((size_t)(s * 4 + wave) * 64 + lane) * 8);
        acc = __builtin_amdgcn_mfma_f32_16x16x32_bf16(ahi.v, b_hi, acc, 0, 0, 0);
        acc = __builtin_amdgcn_mfma_f32_16x16x32_bf16(ahi.v, b_lo, acc, 0, 0, 0);
        acc = __builtin_amdgcn_mfma_f32_16x16x32_bf16(alo.v, b_hi, acc, 0, 0, 0);
    }

    // epilogue: D row=(lane>>4)*4+r (keep rows<8), col=wave*16+(lane&15)
    int dcol = wave * 16 + (lane & 15);
    int rbase = (lane >> 4) * 4;
    if (rbase < 8) {
        float bv = bias[dcol];
#pragma unroll
        for (int r = 0; r < 4; ++r) {
            int nd = node0 + rbase + r;
            float v = fmaxf(acc[r] + bv, 0.0f);
            if (scaleOut) v *= dinv[nd];   // pre-scale for next layer's gather
            hout[(size_t)nd * 64 + dcol] = __float2half(v);
        }
    }
}

// ---------------- pooling: segment sum over sorted batch ids ----------------
__global__ __launch_bounds__(256) void pool_kernel(const __half* __restrict__ h,
                                                   const int* __restrict__ batch,
                                                   float* __restrict__ gpool, int N) {
    const int NPW = 32;  // nodes per wave
    int wid = (blockIdx.x * 256 + threadIdx.x) >> 6;
    int lane = threadIdx.x & 63;
    int i0 = wid * NPW;
    if (i0 >= N) return;
    int i1 = min(i0 + NPW, N);
    int curg = batch[i0];
    float acc = 0.0f;
    for (int i = i0; i < i1; ++i) {
        int g = batch[i];
        if (g != curg) {
            atomicAdd(&gpool[curg * 64 + lane], acc);
            acc = 0.0f;
            curg = g;
        }
        acc += __half2float(h[(size_t)i * 64 + lane]);
    }
    atomicAdd(&gpool[curg * 64 + lane], acc);
}

// ---------------- final: out = (gpool/count) @ Wlin + blin ----------------
__global__ void final_kernel(const float* __restrict__ gpool, const int* __restrict__ gcnt,
                             const float* __restrict__ Wlin, const float* __restrict__ blin,
                             float* __restrict__ out) {
    int t = threadIdx.x;
    if (t >= NGRAPH * COUT) return;
    int g = t / COUT, o = t - g * COUT;
    float c = (float)gcnt[g];
    if (c < 1.0f) c = 1.0f;
    float s = 0.0f;
    for (int k = 0; k < 64; ++k) s += gpool[g * 64 + k] * Wlin[k * COUT + o];
    out[t] = s / c + blin[o];
}

extern "C" void kernel_launch(void* const* d_in, const int* in_sizes, int n_in,
                              void* d_out, int out_size, void* d_ws, size_t ws_size,
                              hipStream_t stream) {
    const float* x    = (const float*)d_in[0];
    const int*   ei   = (const int*)d_in[1];
    const int*   batch= (const int*)d_in[2];
    const float* W0   = (const float*)d_in[3];
    const float* b0   = (const float*)d_in[4];
    const float* Ws   = (const float*)d_in[5];
    const float* bs   = (const float*)d_in[6];
    const float* Wlin = (const float*)d_in[7];
    const float* blin = (const float*)d_in[8];
    float* out = (float*)d_out;

    const int N = NNODES, E = NEDGES;
    const int* srcp = ei;          // edge_index[0]
    const int* dstp = ei + E;      // edge_index[1]

    char* w = (char*)d_ws;
    float* gpool  = (float*)w; w += (size_t)NGRAPH * 64 * 4;
    size_t zero_bytes = (size_t)(w - (char*)d_ws);   // only gpool needs zeroing
    int*   gcnt   = (int*)w;   w += (size_t)NGRAPH * 4;
    float* dinv   = (float*)w; w += (size_t)N * 4;
    int*   rowptr = (int*)w;   w += (size_t)(N + 1) * 4;
    int*   hist   = (int*)w;   w += (size_t)NB * NC * 4;
    int*   btot   = (int*)w;   w += (size_t)NB * 4;
    int*   bbase  = (int*)w;   w += (size_t)(NB + 1) * 4;
    int*   pbt    = (int*)w;   w += (size_t)NB * 4;
    int*   pbbase = (int*)w;   w += (size_t)(NB + 1) * 4;
    int2*  edge_b = (int2*)w;  w += (size_t)E * 8;
    int*   col    = (int*)w;   w += ((size_t)E + 8 * N) * 4;   // padded CSR
    unsigned short* wfh = (unsigned short*)w; w += (size_t)NSTACK * 4096 * 2;
    unsigned short* wfl = (unsigned short*)w; w += (size_t)NSTACK * 4096 * 2;
    __half* bufA  = (__half*)w; w += (size_t)(N + 1) * 64 * 2;  // +zero row N
    __half* bufB  = (__half*)w; w += (size_t)(N + 1) * 64 * 2;

    hipMemsetAsync(d_ws, 0, zero_bytes, stream);

    int nblocks = (N + 255) / 256;       // 391
    int gemmblocks = (N + 63) / 64;      // 1563: 16 rows/wave (MFMA), 4 waves/block

    pack_wfrags_kernel<<<NSTACK * 8, 256, 0, stream>>>(Ws, wfh, wfl);
    // P1 histogram + layer-0 MFMA GEMM co-scheduled (independent)
    hist_gemm_kernel<<<NC + gemmblocks, 256, 0, stream>>>(
        dstp, hist, E, x, W0, bufB, N, NC);
    scan_chunks_kernel<<<NB, 256, 0, stream>>>(hist, btot);
    scan_buckets_kernel<<<1, 512, 0, stream>>>(btot, bbase);
    scatter_kernel<<<NC * 8, 256, 0, stream>>>(srcp, dstp, hist, bbase, edge_b, E);
    bucket_prep_kernel<<<NB + 1, 256, 0, stream>>>(edge_b, bbase, btot, rowptr, pbt, dinv,
                                                   batch, gcnt, N);
    scan_buckets_kernel<<<1, 512, 0, stream>>>(pbt, pbbase);
    rowptr_fix_kernel<<<nblocks, 256, 0, stream>>>(rowptr, pbbase, N);
    bucket_fill_kernel<<<NB, 256, 0, stream>>>(edge_b, bbase, btot, rowptr, col, N);
    scale_m_kernel<<<2048, 256, 0, stream>>>(bufB, bufA, dinv, N);

    int pairblocks = (N / 2 + 3) / 4;     // 2 nodes/wave, 4 waves/block (agg0)
    int fusedblocks = N / 8;              // 8 nodes/block (fused, MFMA GEMM)

    agg0_kernel<<<pairblocks, 256, 0, stream>>>(bufB, rowptr, col, dinv, b0, bufA, N);

    // layers 1..9 fused: h' = relu((A h) W + b); rows pre-scaled except the last
    __half* hin = bufA;
    __half* hout = bufB;
    for (int l = 0; l < NSTACK; ++l) {
        int scaleOut = (l < NSTACK - 1) ? 1 : 0;
        fused_kernel<<<fusedblocks, 256, 0, stream>>>(hin, rowptr, col, dinv,
                                                      wfh + (size_t)l * 4096,
                                                      wfl + (size_t)l * 4096,
                                                      bs + (size_t)l * 64, hout, N,
                                                      scaleOut);
        __half* t = hin; hin = hout; hout = t;
    }
    // final h is in `hin` after the swap

    int pwaves = (N + 31) / 32;
    int pblocks = (pwaves + 3) / 4;
    pool_kernel<<<pblocks, 256, 0, stream>>>(hin, batch, gpool, N);
    final_kernel<<<1, 896, 0, stream>>>(gpool, gcnt, Wlin, blin, out);
}